// Round 2
// baseline (308.070 us; speedup 1.0000x reference)
//
#include <hip/hip_runtime.h>
#include <hip/hip_bf16.h>

#define NEG_INF -9.0e15f

__device__ __forceinline__ float b2f(__hip_bfloat16 v) { return __bfloat162float(v); }

__device__ __forceinline__ float ldf(const void* p, int i, int isbf) {
    return isbf ? b2f(((const __hip_bfloat16*)p)[i]) : ((const float*)p)[i];
}

__device__ __forceinline__ float wave_max(float v) {
    for (int off = 32; off > 0; off >>= 1) v = fmaxf(v, __shfl_down(v, off, 64));
    return v;
}
__device__ __forceinline__ float wave_sum(float v) {
    for (int off = 32; off > 0; off >>= 1) v += __shfl_down(v, off, 64);
    return v;
}

// Decide whether float inputs are bf16 (flag=1) or f32 (flag=0).
__global__ void k_sniff(const unsigned short* __restrict__ w, int* __restrict__ flag) {
    if (threadIdx.x == 0 && blockIdx.x == 0) {
        int sane = 0;
        for (int k = 0; k < 64; ++k) {
            unsigned short u = w[2 * k];
            int e = (u >> 7) & 0xFF;
            if (e >= 100 && e <= 140) ++sane;
        }
        *flag = (sane >= 48) ? 1 : 0;
    }
}

__global__ __launch_bounds__(256) void k_node_proj(
    const void* __restrict__ nf, const void* __restrict__ Wn,
    const void* __restrict__ bn, float* __restrict__ x,
    const int* __restrict__ flag) {
    const int isbf = *flag;
    int row = blockIdx.x;
    int j = threadIdx.x;
    __shared__ float xs[78];
    if (j < 78) xs[j] = ldf(nf, row * 78 + j, isbf);
    __syncthreads();
    float acc = ldf(bn, j, isbf);
    if (isbf) {
        const __hip_bfloat16* W = (const __hip_bfloat16*)Wn;
        #pragma unroll 6
        for (int k = 0; k < 78; ++k) acc += xs[k] * b2f(W[k * 256 + j]);
    } else {
        const float* W = (const float*)Wn;
        #pragma unroll 6
        for (int k = 0; k < 78; ++k) acc += xs[k] * W[k * 256 + j];
    }
    x[row * 256 + j] = acc;
}

__global__ __launch_bounds__(256) void k_wa(
    const void* __restrict__ gat_W, const void* __restrict__ gat_a,
    float* __restrict__ wa, const int* __restrict__ flag) {
    const int isbf = *flag;
    int l = blockIdx.x;
    int k = threadIdx.x;
    float acc1 = 0.f, acc2 = 0.f;
    if (isbf) {
        const __hip_bfloat16* W = (const __hip_bfloat16*)gat_W + l * 65536;
        const __hip_bfloat16* a = (const __hip_bfloat16*)gat_a + l * 512;
        for (int j = 0; j < 256; ++j) {
            float w = b2f(W[k * 256 + j]);
            acc1 += w * b2f(a[j]);
            acc2 += w * b2f(a[256 + j]);
        }
    } else {
        const float* W = (const float*)gat_W + l * 65536;
        const float* a = (const float*)gat_a + l * 512;
        for (int j = 0; j < 256; ++j) {
            float w = W[k * 256 + j];
            acc1 += w * a[j];
            acc2 += w * a[256 + j];
        }
    }
    wa[l * 512 + k] = acc1;
    wa[l * 512 + 256 + k] = acc2;
}

// h = x @ W[l]; s1 = x@wa1; s2 = x@wa2.  8 rows per block. Layer offset inside.
__global__ __launch_bounds__(256) void k_gat_h(
    const float* __restrict__ x, const void* __restrict__ gat_W, int layer,
    const float* __restrict__ wa_l, float* __restrict__ h,
    float* __restrict__ s1, float* __restrict__ s2,
    const int* __restrict__ flag) {
    const int isbf = *flag;
    int row0 = blockIdx.x * 8;
    int j = threadIdx.x;
    __shared__ float xs[8][256];
    __shared__ float red[256][16];
    #pragma unroll
    for (int r = 0; r < 8; ++r) xs[r][j] = x[(row0 + r) * 256 + j];
    __syncthreads();
    float acc[8];
    #pragma unroll
    for (int r = 0; r < 8; ++r) acc[r] = 0.f;
    if (isbf) {
        const __hip_bfloat16* W = (const __hip_bfloat16*)gat_W + (size_t)layer * 65536;
        for (int k = 0; k < 256; ++k) {
            float w = b2f(W[k * 256 + j]);
            #pragma unroll
            for (int r = 0; r < 8; ++r) acc[r] += xs[r][k] * w;
        }
    } else {
        const float* W = (const float*)gat_W + (size_t)layer * 65536;
        for (int k = 0; k < 256; ++k) {
            float w = W[k * 256 + j];
            #pragma unroll
            for (int r = 0; r < 8; ++r) acc[r] += xs[r][k] * w;
        }
    }
    #pragma unroll
    for (int r = 0; r < 8; ++r) h[(row0 + r) * 256 + j] = acc[r];
    float wa1 = wa_l[j], wa2 = wa_l[256 + j];
    #pragma unroll
    for (int r = 0; r < 8; ++r) {
        red[j][2 * r]     = xs[r][j] * wa1;
        red[j][2 * r + 1] = xs[r][j] * wa2;
    }
    __syncthreads();
    for (int s = 128; s > 0; s >>= 1) {
        if (j < s) {
            #pragma unroll
            for (int q = 0; q < 16; ++q) red[j][q] += red[j + s][q];
        }
        __syncthreads();
    }
    if (j < 8) {
        s1[row0 + j] = red[0][2 * j];
        s2[row0 + j] = red[0][2 * j + 1];
    }
}

__global__ __launch_bounds__(256) void k_attn(
    const float* __restrict__ h, const float* __restrict__ s1,
    const float* __restrict__ s2, const int* __restrict__ adj,
    float* __restrict__ x) {
    int blk = blockIdx.x;
    int b = blk >> 4;
    int i0 = (blk & 15) * 8;
    int t = threadIdx.x;
    __shared__ float att[8][128];
    __shared__ float s2s[128];
    __shared__ float wredm[4];
    __shared__ float wreds[4];
    if (t < 128) s2s[t] = s2[b * 128 + t];
    __syncthreads();
    int half = t >> 7;
    int c = t & 127;
    int w = t >> 6;
    int wbase = half << 1;
    for (int rp = 0; rp < 4; ++rp) {
        int r = rp * 2 + half;
        int i = i0 + r;
        float e = s1[b * 128 + i] + s2s[c];
        e = (e >= 0.f) ? e : 0.2f * e;
        float v = (adj[(b * 128 + i) * 128 + c] > 0) ? e : NEG_INF;
        float m = wave_max(v);
        if ((t & 63) == 0) wredm[w] = m;
        __syncthreads();
        m = fmaxf(wredm[wbase], wredm[wbase + 1]);
        float p = expf(v - m);
        float ssum = wave_sum(p);
        if ((t & 63) == 0) wreds[w] = ssum;
        __syncthreads();
        float denom = wreds[wbase] + wreds[wbase + 1];
        att[r][c] = p / denom;
    }
    __syncthreads();
    float acc[8];
    #pragma unroll
    for (int r = 0; r < 8; ++r) acc[r] = 0.f;
    const float* hb = h + (size_t)b * 128 * 256;
    for (int j = 0; j < 128; ++j) {
        float hv = hb[j * 256 + t];
        #pragma unroll
        for (int r = 0; r < 8; ++r) acc[r] += att[r][j] * hv;
    }
    #pragma unroll
    for (int r = 0; r < 8; ++r)
        x[(size_t)(b * 128 + i0 + r) * 256 + t] = fmaxf(acc[r], 0.f);
}

__global__ __launch_bounds__(256) void k_head(
    const float* __restrict__ x, const void* __restrict__ scaf,
    const void* __restrict__ W_sc, const void* __restrict__ b_sc,
    const void* __restrict__ gp_w1, const void* __restrict__ gp_b1,
    const void* __restrict__ gp_w2, const void* __restrict__ gp_b2,
    const void* __restrict__ out_w1, const void* __restrict__ out_b1,
    const void* __restrict__ out_w2, const void* __restrict__ out_b2,
    void* __restrict__ out, const int* __restrict__ flag) {
    const int isbf = *flag;
    int b = blockIdx.x;
    int t = threadIdx.x;
    __shared__ float gin[256], sproj[256], z1g[128], z1s[128], cvec[128], hdn[128];
    const float* xb = x + (size_t)b * 128 * 256;
    float acc = 0.f;
    for (int n = 0; n < 128; ++n) acc += xb[n * 256 + t];
    gin[t] = acc * (1.f / 128.f);
    float sa = ldf(b_sc, t, isbf);
    for (int k = 0; k < 20; ++k)
        sa += ldf(scaf, b * 20 + k, isbf) * ldf(W_sc, k * 256 + t, isbf);
    sproj[t] = sa;
    __syncthreads();
    if (t < 128) {
        float a1 = ldf(gp_b1, t, isbf);
        float a2 = a1;
        for (int k = 0; k < 256; ++k) {
            float w = ldf(gp_w1, k * 128 + t, isbf);
            a1 += gin[k] * w;
            a2 += sproj[k] * w;
        }
        z1g[t] = fmaxf(a1, 0.f);
        z1s[t] = fmaxf(a2, 0.f);
    }
    __syncthreads();
    if (t < 64) {
        float a1 = ldf(gp_b2, t, isbf);
        float a2 = a1;
        for (int k = 0; k < 128; ++k) {
            float w = ldf(gp_w2, k * 64 + t, isbf);
            a1 += z1g[k] * w;
            a2 += z1s[k] * w;
        }
        cvec[t] = fmaxf(a1, 0.f);
        cvec[64 + t] = fmaxf(a2, 0.f);
    }
    __syncthreads();
    if (t < 128) {
        float a = ldf(out_b1, t, isbf);
        for (int k = 0; k < 128; ++k) a += cvec[k] * ldf(out_w1, k * 128 + t, isbf);
        hdn[t] = fmaxf(a, 0.f);
    }
    __syncthreads();
    if (t < 13) {
        float a = ldf(out_b2, t, isbf);
        for (int k = 0; k < 128; ++k) a += hdn[k] * ldf(out_w2, k * 13 + t, isbf);
        if (isbf) ((__hip_bfloat16*)out)[b * 13 + t] = __float2bfloat16(a);
        else      ((float*)out)[b * 13 + t] = a;
    }
}

extern "C" void kernel_launch(void* const* d_in, const int* in_sizes, int n_in,
                              void* d_out, int out_size, void* d_ws, size_t ws_size,
                              hipStream_t stream) {
    (void)in_sizes; (void)n_in; (void)out_size; (void)ws_size;
    const void* nf     = d_in[0];
    const int*  adj    = (const int*)d_in[2];
    const void* scaf   = d_in[3];
    const void* W_node = d_in[4];
    const void* b_node = d_in[5];
    const void* gat_W  = d_in[6];
    const void* gat_a  = d_in[7];
    const void* W_sc   = d_in[8];
    const void* b_sc   = d_in[9];
    const void* gp_w1  = d_in[10];
    const void* gp_b1  = d_in[11];
    const void* gp_w2  = d_in[12];
    const void* gp_b2  = d_in[13];
    const void* out_w1 = d_in[14];
    const void* out_b1 = d_in[15];
    const void* out_w2 = d_in[16];
    const void* out_b2 = d_in[17];

    float* ws = (float*)d_ws;
    float* x  = ws;
    float* h  = ws + 1048576;
    float* s1 = ws + 2097152;
    float* s2 = s1 + 4096;
    float* wa = s2 + 4096;
    int* flag = (int*)(wa + 1536);

    k_sniff<<<1, 1, 0, stream>>>((const unsigned short*)W_node, flag);
    k_node_proj<<<4096, 256, 0, stream>>>(nf, W_node, b_node, x, flag);
    k_wa<<<3, 256, 0, stream>>>(gat_W, gat_a, wa, flag);
    for (int l = 0; l < 3; ++l) {
        k_gat_h<<<512, 256, 0, stream>>>(x, gat_W, l, wa + l * 512, h, s1, s2, flag);
        k_attn<<<512, 256, 0, stream>>>(h, s1, s2, adj, x);
    }
    k_head<<<32, 256, 0, stream>>>(x, scaf, W_sc, b_sc, gp_w1, gp_b1, gp_w2, gp_b2,
                                   out_w1, out_b1, out_w2, out_b2, d_out, flag);
}

// Round 3
// 266.666 us; speedup vs baseline: 1.1553x; 1.1553x over previous
//
#include <hip/hip_runtime.h>
#include <hip/hip_bf16.h>

#define NEG_INF -9.0e15f

__device__ __forceinline__ float b2f(__hip_bfloat16 v) { return __bfloat162float(v); }

__device__ __forceinline__ float ldv(const float* p, int i) { return p[i]; }
__device__ __forceinline__ float ldv(const __hip_bfloat16* p, int i) { return __bfloat162float(p[i]); }

__device__ __forceinline__ float wave_max(float v) {
    for (int off = 32; off > 0; off >>= 1) v = fmaxf(v, __shfl_down(v, off, 64));
    return v;
}
__device__ __forceinline__ float wave_sum(float v) {
    for (int off = 32; off > 0; off >>= 1) v += __shfl_down(v, off, 64);
    return v;
}

// Decide whether float inputs are bf16 (flag=1) or f32 (flag=0).
__global__ void k_sniff(const unsigned short* __restrict__ w, int* __restrict__ flag) {
    if (threadIdx.x == 0 && blockIdx.x == 0) {
        int sane = 0;
        for (int k = 0; k < 64; ++k) {
            unsigned short u = w[2 * k];
            int e = (u >> 7) & 0xFF;
            if (e >= 100 && e <= 140) ++sane;
        }
        *flag = (sane >= 48) ? 1 : 0;
    }
}

__global__ __launch_bounds__(256) void k_node_proj(
    const void* __restrict__ nf, const void* __restrict__ Wn,
    const void* __restrict__ bn, float* __restrict__ x,
    const int* __restrict__ flag) {
    const int isbf = *flag;
    int row = blockIdx.x;
    int j = threadIdx.x;
    __shared__ float xs[78];
    if (j < 78) xs[j] = isbf ? ldv((const __hip_bfloat16*)nf, row * 78 + j)
                             : ldv((const float*)nf, row * 78 + j);
    __syncthreads();
    float acc = isbf ? ldv((const __hip_bfloat16*)bn, j) : ldv((const float*)bn, j);
    if (isbf) {
        const __hip_bfloat16* W = (const __hip_bfloat16*)Wn;
        #pragma unroll 6
        for (int k = 0; k < 78; ++k) acc += xs[k] * b2f(W[k * 256 + j]);
    } else {
        const float* W = (const float*)Wn;
        #pragma unroll 6
        for (int k = 0; k < 78; ++k) acc += xs[k] * W[k * 256 + j];
    }
    x[row * 256 + j] = acc;
}

__global__ __launch_bounds__(256) void k_wa(
    const void* __restrict__ gat_W, const void* __restrict__ gat_a,
    float* __restrict__ wa, const int* __restrict__ flag) {
    const int isbf = *flag;
    int l = blockIdx.x;
    int k = threadIdx.x;
    float acc1 = 0.f, acc2 = 0.f;
    if (isbf) {
        const __hip_bfloat16* W = (const __hip_bfloat16*)gat_W + l * 65536;
        const __hip_bfloat16* a = (const __hip_bfloat16*)gat_a + l * 512;
        #pragma unroll 8
        for (int j = 0; j < 256; ++j) {
            float w = b2f(W[k * 256 + j]);
            acc1 += w * b2f(a[j]);
            acc2 += w * b2f(a[256 + j]);
        }
    } else {
        const float* W = (const float*)gat_W + l * 65536;
        const float* a = (const float*)gat_a + l * 512;
        #pragma unroll 8
        for (int j = 0; j < 256; ++j) {
            float w = W[k * 256 + j];
            acc1 += w * a[j];
            acc2 += w * a[256 + j];
        }
    }
    wa[l * 512 + k] = acc1;
    wa[l * 512 + 256 + k] = acc2;
}

// h = x @ W[l]; s1 = x@wa1; s2 = x@wa2.  8 rows per block.
__global__ __launch_bounds__(256) void k_gat_h(
    const float* __restrict__ x, const void* __restrict__ gat_W, int layer,
    const float* __restrict__ wa_l, float* __restrict__ h,
    float* __restrict__ s1, float* __restrict__ s2,
    const int* __restrict__ flag) {
    const int isbf = *flag;
    int row0 = blockIdx.x * 8;
    int j = threadIdx.x;
    __shared__ float xs[8][256];
    __shared__ float red[256][16];
    #pragma unroll
    for (int r = 0; r < 8; ++r) xs[r][j] = x[(row0 + r) * 256 + j];
    __syncthreads();
    float acc[8];
    #pragma unroll
    for (int r = 0; r < 8; ++r) acc[r] = 0.f;
    if (isbf) {
        const __hip_bfloat16* W = (const __hip_bfloat16*)gat_W + (size_t)layer * 65536;
        #pragma unroll 4
        for (int k = 0; k < 256; ++k) {
            float w = b2f(W[k * 256 + j]);
            #pragma unroll
            for (int r = 0; r < 8; ++r) acc[r] += xs[r][k] * w;
        }
    } else {
        const float* W = (const float*)gat_W + (size_t)layer * 65536;
        #pragma unroll 4
        for (int k = 0; k < 256; ++k) {
            float w = W[k * 256 + j];
            #pragma unroll
            for (int r = 0; r < 8; ++r) acc[r] += xs[r][k] * w;
        }
    }
    #pragma unroll
    for (int r = 0; r < 8; ++r) h[(row0 + r) * 256 + j] = acc[r];
    float wa1 = wa_l[j], wa2 = wa_l[256 + j];
    #pragma unroll
    for (int r = 0; r < 8; ++r) {
        red[j][2 * r]     = xs[r][j] * wa1;
        red[j][2 * r + 1] = xs[r][j] * wa2;
    }
    __syncthreads();
    for (int s = 128; s > 0; s >>= 1) {
        if (j < s) {
            #pragma unroll
            for (int q = 0; q < 16; ++q) red[j][q] += red[j + s][q];
        }
        __syncthreads();
    }
    if (j < 8) {
        s1[row0 + j] = red[0][2 * j];
        s2[row0 + j] = red[0][2 * j + 1];
    }
}

// attention softmax + h_prime = att@h.  8 i-rows per block.
// do_pool=0: x = relu(h_prime).  do_pool=1: atomicAdd relu'd row-sums/128 into gin.
__global__ __launch_bounds__(256) void k_attn(
    const float* __restrict__ h, const float* __restrict__ s1,
    const float* __restrict__ s2, const int* __restrict__ adj,
    float* __restrict__ x, float* __restrict__ gin, int do_pool) {
    int blk = blockIdx.x;
    int b = blk >> 4;
    int i0 = (blk & 15) * 8;
    int t = threadIdx.x;
    __shared__ float att[8][128];
    __shared__ float s2s[128];
    __shared__ float wredm[4];
    __shared__ float wreds[4];
    if (t < 128) s2s[t] = s2[b * 128 + t];
    __syncthreads();
    int half = t >> 7;
    int c = t & 127;
    int w = t >> 6;
    int wbase = half << 1;
    for (int rp = 0; rp < 4; ++rp) {
        int r = rp * 2 + half;
        int i = i0 + r;
        float e = s1[b * 128 + i] + s2s[c];
        e = (e >= 0.f) ? e : 0.2f * e;
        float v = (adj[(b * 128 + i) * 128 + c] > 0) ? e : NEG_INF;
        float m = wave_max(v);
        if ((t & 63) == 0) wredm[w] = m;
        __syncthreads();
        m = fmaxf(wredm[wbase], wredm[wbase + 1]);
        float p = expf(v - m);
        float ssum = wave_sum(p);
        if ((t & 63) == 0) wreds[w] = ssum;
        __syncthreads();
        float denom = wreds[wbase] + wreds[wbase + 1];
        att[r][c] = p / denom;
    }
    __syncthreads();
    float acc[8];
    #pragma unroll
    for (int r = 0; r < 8; ++r) acc[r] = 0.f;
    const float* hb = h + (size_t)b * 128 * 256;
    #pragma unroll 4
    for (int j = 0; j < 128; ++j) {
        float hv = hb[j * 256 + t];
        #pragma unroll
        for (int r = 0; r < 8; ++r) acc[r] += att[r][j] * hv;
    }
    if (do_pool) {
        float s = 0.f;
        #pragma unroll
        for (int r = 0; r < 8; ++r) s += fmaxf(acc[r], 0.f);
        atomicAdd(&gin[b * 256 + t], s * (1.f / 128.f));
    } else {
        #pragma unroll
        for (int r = 0; r < 8; ++r)
            x[(size_t)(b * 128 + i0 + r) * 256 + t] = fmaxf(acc[r], 0.f);
    }
}

// Head body templated on weight dtype; all K-loops parallelized across threads
// with LDS tree-reduction. smem arrays passed in from kernel (single set).
template <typename T>
__device__ __forceinline__ void head_body(
    int b, int t, const float* __restrict__ gin,
    const T* scaf, const T* W_sc, const T* b_sc,
    const T* gp_w1, const T* gp_b1, const T* gp_w2, const T* gp_b2,
    const T* out_w1, const T* out_b1, const T* out_w2, const T* out_b2,
    float* gin_s, float* sproj, float* scaf_s,
    float* red1, float* red2, float* z1g, float* z1s,
    float* cvec, float* hdn, float* outv) {
    gin_s[t] = gin[b * 256 + t];
    if (t < 20) scaf_s[t] = ldv(scaf, b * 20 + t);
    __syncthreads();
    // scaffold projection (20-deep, fully unrolled)
    {
        float sa = ldv(b_sc, t);
        #pragma unroll
        for (int k = 0; k < 20; ++k) sa += scaf_s[k] * ldv(W_sc, k * 256 + t);
        sproj[t] = sa;
    }
    __syncthreads();
    // gp layer1: 256 -> 128, thread = (j, k-half)
    {
        int j = t & 127, khalf = t >> 7;
        int k0 = khalf * 128;
        float a1 = 0.f, a2 = 0.f;
        #pragma unroll 8
        for (int kk = 0; kk < 128; ++kk) {
            int k = k0 + kk;
            float wv = ldv(gp_w1, k * 128 + j);
            a1 += gin_s[k] * wv;
            a2 += sproj[k] * wv;
        }
        red1[t] = a1; red2[t] = a2;
    }
    __syncthreads();
    if (t < 128) {
        float bb = ldv(gp_b1, t);
        z1g[t] = fmaxf(bb + red1[t] + red1[t + 128], 0.f);
        z1s[t] = fmaxf(bb + red2[t] + red2[t + 128], 0.f);
    }
    __syncthreads();
    // gp layer2: 128 -> 64, thread = (j, k-quarter)
    {
        int j = t & 63, q = t >> 6;
        int k0 = q * 32;
        float a1 = 0.f, a2 = 0.f;
        #pragma unroll
        for (int kk = 0; kk < 32; ++kk) {
            int k = k0 + kk;
            float wv = ldv(gp_w2, k * 64 + j);
            a1 += z1g[k] * wv;
            a2 += z1s[k] * wv;
        }
        red1[t] = a1; red2[t] = a2;
    }
    __syncthreads();
    if (t < 64) {
        float bb = ldv(gp_b2, t);
        cvec[t]      = fmaxf(bb + red1[t] + red1[t + 64] + red1[t + 128] + red1[t + 192], 0.f);
        cvec[64 + t] = fmaxf(bb + red2[t] + red2[t + 64] + red2[t + 128] + red2[t + 192], 0.f);
    }
    __syncthreads();
    // out layer1: 128 -> 128, thread = (j, k-half)
    {
        int j = t & 127, khalf = t >> 7;
        int k0 = khalf * 64;
        float a = 0.f;
        #pragma unroll 8
        for (int kk = 0; kk < 64; ++kk) {
            int k = k0 + kk;
            a += cvec[k] * ldv(out_w1, k * 128 + j);
        }
        red1[t] = a;
    }
    __syncthreads();
    if (t < 128) hdn[t] = fmaxf(ldv(out_b1, t) + red1[t] + red1[t + 128], 0.f);
    __syncthreads();
    // out layer2: 128 -> 13
    if (t < 13) {
        float a = ldv(out_b2, t);
        #pragma unroll 8
        for (int k = 0; k < 128; ++k) a += hdn[k] * ldv(out_w2, k * 13 + t);
        outv[t] = a;
    }
}

__global__ __launch_bounds__(256) void k_head(
    const float* __restrict__ gin, const void* __restrict__ scaf,
    const void* __restrict__ W_sc, const void* __restrict__ b_sc,
    const void* __restrict__ gp_w1, const void* __restrict__ gp_b1,
    const void* __restrict__ gp_w2, const void* __restrict__ gp_b2,
    const void* __restrict__ out_w1, const void* __restrict__ out_b1,
    const void* __restrict__ out_w2, const void* __restrict__ out_b2,
    void* __restrict__ out, const int* __restrict__ flag) {
    const int isbf = *flag;
    int b = blockIdx.x;
    int t = threadIdx.x;
    __shared__ float gin_s[256], sproj[256], scaf_s[20];
    __shared__ float red1[256], red2[256];
    __shared__ float z1g[128], z1s[128], cvec[128], hdn[128], outv[13];
    if (isbf) {
        head_body<__hip_bfloat16>(b, t, gin,
            (const __hip_bfloat16*)scaf, (const __hip_bfloat16*)W_sc, (const __hip_bfloat16*)b_sc,
            (const __hip_bfloat16*)gp_w1, (const __hip_bfloat16*)gp_b1,
            (const __hip_bfloat16*)gp_w2, (const __hip_bfloat16*)gp_b2,
            (const __hip_bfloat16*)out_w1, (const __hip_bfloat16*)out_b1,
            (const __hip_bfloat16*)out_w2, (const __hip_bfloat16*)out_b2,
            gin_s, sproj, scaf_s, red1, red2, z1g, z1s, cvec, hdn, outv);
    } else {
        head_body<float>(b, t, gin,
            (const float*)scaf, (const float*)W_sc, (const float*)b_sc,
            (const float*)gp_w1, (const float*)gp_b1,
            (const float*)gp_w2, (const float*)gp_b2,
            (const float*)out_w1, (const float*)out_b1,
            (const float*)out_w2, (const float*)out_b2,
            gin_s, sproj, scaf_s, red1, red2, z1g, z1s, cvec, hdn, outv);
    }
    __syncthreads();
    if (t < 13) {
        if (isbf) ((__hip_bfloat16*)out)[b * 13 + t] = __float2bfloat16(outv[t]);
        else      ((float*)out)[b * 13 + t] = outv[t];
    }
}

extern "C" void kernel_launch(void* const* d_in, const int* in_sizes, int n_in,
                              void* d_out, int out_size, void* d_ws, size_t ws_size,
                              hipStream_t stream) {
    (void)in_sizes; (void)n_in; (void)out_size; (void)ws_size;
    const void* nf     = d_in[0];
    const int*  adj    = (const int*)d_in[2];
    const void* scaf   = d_in[3];
    const void* W_node = d_in[4];
    const void* b_node = d_in[5];
    const void* gat_W  = d_in[6];
    const void* gat_a  = d_in[7];
    const void* W_sc   = d_in[8];
    const void* b_sc   = d_in[9];
    const void* gp_w1  = d_in[10];
    const void* gp_b1  = d_in[11];
    const void* gp_w2  = d_in[12];
    const void* gp_b2  = d_in[13];
    const void* out_w1 = d_in[14];
    const void* out_b1 = d_in[15];
    const void* out_w2 = d_in[16];
    const void* out_b2 = d_in[17];

    float* ws  = (float*)d_ws;
    float* x   = ws;                    // 1048576 floats
    float* h   = ws + 1048576;          // 1048576 floats
    float* s1  = ws + 2097152;          // 4096
    float* s2  = s1 + 4096;             // 4096
    float* wa  = s2 + 4096;             // 1536
    int*  flag = (int*)(wa + 1536);     // 1 (padded to 4)
    float* gin = (float*)(flag + 4);    // 8192 floats

    hipMemsetAsync(gin, 0, 32 * 256 * sizeof(float), stream);
    k_sniff<<<1, 1, 0, stream>>>((const unsigned short*)W_node, flag);
    k_node_proj<<<4096, 256, 0, stream>>>(nf, W_node, b_node, x, flag);
    k_wa<<<3, 256, 0, stream>>>(gat_W, gat_a, wa, flag);
    for (int l = 0; l < 3; ++l) {
        k_gat_h<<<512, 256, 0, stream>>>(x, gat_W, l, wa + l * 512, h, s1, s2, flag);
        k_attn<<<512, 256, 0, stream>>>(h, s1, s2, adj, x, gin, (l == 2) ? 1 : 0);
    }
    k_head<<<32, 256, 0, stream>>>(gin, scaf, W_sc, b_sc, gp_w1, gp_b1, gp_w2, gp_b2,
                                   out_w1, out_b1, out_w2, out_b2, d_out, flag);
}

// Round 4
// 266.157 us; speedup vs baseline: 1.1575x; 1.0019x over previous
//
#include <hip/hip_runtime.h>
#include <hip/hip_bf16.h>

#define NEG_INF -9.0e15f

__device__ __forceinline__ float b2f(__hip_bfloat16 v) { return __bfloat162float(v); }
__device__ __forceinline__ float ldv(const float* p, int i) { return p[i]; }
__device__ __forceinline__ float ldv(const __hip_bfloat16* p, int i) { return __bfloat162float(p[i]); }

// 8 consecutive values -> f32 (16B-aligned pointer required for bf16 path)
__device__ __forceinline__ void ld8f(const float* p, float* f) {
    const float4* q = (const float4*)p;
    float4 a = q[0], b = q[1];
    f[0]=a.x; f[1]=a.y; f[2]=a.z; f[3]=a.w; f[4]=b.x; f[5]=b.y; f[6]=b.z; f[7]=b.w;
}
__device__ __forceinline__ void ld8f(const __hip_bfloat16* p, float* f) {
    uint4 r = *(const uint4*)p;
    f[0]=__uint_as_float(r.x<<16); f[1]=__uint_as_float(r.x&0xffff0000u);
    f[2]=__uint_as_float(r.y<<16); f[3]=__uint_as_float(r.y&0xffff0000u);
    f[4]=__uint_as_float(r.z<<16); f[5]=__uint_as_float(r.z&0xffff0000u);
    f[6]=__uint_as_float(r.w<<16); f[7]=__uint_as_float(r.w&0xffff0000u);
}

// wave-level dtype sniff: bf16 weights have sane exponents at every u16;
// f32 weights' even u16s are uniform mantissa bits (~16% sane). Uniform per wave.
__device__ __forceinline__ int sniff(const void* wnode) {
    const unsigned short* w = (const unsigned short*)wnode;
    int lane = threadIdx.x & 63;
    unsigned short u = w[2 * lane];
    int e = (u >> 7) & 0xFF;
    unsigned long long m = __ballot(e >= 100 && e <= 140);
    return __popcll(m) >= 48;
}

// ---------------- gat_h: h = x @ W[l]; s1 = h@a1; s2 = h@a2 -----------------
// 512 blocks x 256 thr. Block = 8 rows x 256 cols. Thread: 1 row (ty=t>>5),
// 8 cols (8*tx, tx=t&31). first=1: build x rows from nf@W_node+b in-kernel.
template <typename T>
__device__ __forceinline__ void gat_h_body(
    int row0, int t, const T* __restrict__ Wl, const T* __restrict__ ga,
    const T* __restrict__ nf, const T* __restrict__ Wn, const T* __restrict__ bn,
    const float* __restrict__ x, int first,
    float* __restrict__ h, float* __restrict__ s1, float* __restrict__ s2,
    float (*xs)[256], float (*nfs)[80]) {
    int tx = t & 31, ty = t >> 5;
    if (first) {
        for (int idx = t; idx < 624; idx += 256) {
            int r = idx / 78, k = idx - r * 78;
            nfs[r][k] = ldv(nf, (row0 + r) * 78 + k);
        }
        __syncthreads();
        float acc[8];
        ld8f(bn + 8 * tx, acc);
        for (int k = 0; k < 78; ++k) {
            float xv = nfs[ty][k];
            float w8[8]; ld8f(Wn + k * 256 + 8 * tx, w8);
            #pragma unroll
            for (int c = 0; c < 8; ++c) acc[c] += xv * w8[c];
        }
        #pragma unroll
        for (int c = 0; c < 8; ++c) xs[ty][8 * tx + c] = acc[c];
        __syncthreads();
    } else {
        for (int f = t; f < 512; f += 256) {
            int r = f >> 6, pos = f & 63;
            ((float4*)&xs[r][0])[pos] = ((const float4*)&x[(size_t)(row0 + r) * 256])[pos];
        }
        __syncthreads();
    }
    float acc[8];
    #pragma unroll
    for (int c = 0; c < 8; ++c) acc[c] = 0.f;
    #pragma unroll 2
    for (int k0 = 0; k0 < 256; k0 += 4) {
        float4 xv = *(const float4*)&xs[ty][k0];
        float w0[8], w1[8], w2[8], w3[8];
        ld8f(Wl + (k0 + 0) * 256 + 8 * tx, w0);
        ld8f(Wl + (k0 + 1) * 256 + 8 * tx, w1);
        ld8f(Wl + (k0 + 2) * 256 + 8 * tx, w2);
        ld8f(Wl + (k0 + 3) * 256 + 8 * tx, w3);
        #pragma unroll
        for (int c = 0; c < 8; ++c)
            acc[c] += xv.x * w0[c] + xv.y * w1[c] + xv.z * w2[c] + xv.w * w3[c];
    }
    // s1/s2 from register h (= x@(W@a) by associativity; ref computes h@a)
    float a1v[8], a2v[8];
    ld8f(ga + 8 * tx, a1v);
    ld8f(ga + 256 + 8 * tx, a2v);
    float d1 = 0.f, d2 = 0.f;
    #pragma unroll
    for (int c = 0; c < 8; ++c) { d1 += acc[c] * a1v[c]; d2 += acc[c] * a2v[c]; }
    #pragma unroll
    for (int off = 1; off < 32; off <<= 1) {
        d1 += __shfl_xor(d1, off, 64);
        d2 += __shfl_xor(d2, off, 64);
    }
    int row = row0 + ty;
    if (tx == 0) { s1[row] = d1; s2[row] = d2; }
    float4 h0 = {acc[0], acc[1], acc[2], acc[3]};
    float4 h1 = {acc[4], acc[5], acc[6], acc[7]};
    *(float4*)&h[(size_t)row * 256 + 8 * tx]     = h0;
    *(float4*)&h[(size_t)row * 256 + 8 * tx + 4] = h1;
}

__global__ __launch_bounds__(256) void k_gat_h(
    const float* __restrict__ x, const void* __restrict__ gat_W,
    const void* __restrict__ gat_a, int layer,
    const void* __restrict__ nf, const void* __restrict__ Wn,
    const void* __restrict__ bn, int first,
    float* __restrict__ h, float* __restrict__ s1, float* __restrict__ s2) {
    __shared__ float xs[8][256];
    __shared__ float nfs[8][80];
    int row0 = blockIdx.x * 8;
    int t = threadIdx.x;
    if (sniff(Wn)) {
        gat_h_body<__hip_bfloat16>(row0, t,
            (const __hip_bfloat16*)gat_W + (size_t)layer * 65536,
            (const __hip_bfloat16*)gat_a + (size_t)layer * 512,
            (const __hip_bfloat16*)nf, (const __hip_bfloat16*)Wn,
            (const __hip_bfloat16*)bn, x, first, h, s1, s2, xs, nfs);
    } else {
        gat_h_body<float>(row0, t,
            (const float*)gat_W + (size_t)layer * 65536,
            (const float*)gat_a + (size_t)layer * 512,
            (const float*)nf, (const float*)Wn, (const float*)bn,
            x, first, h, s1, s2, xs, nfs);
    }
}

// ---------------- attn: softmax(mask(leaky(s1+s2))) @ h ---------------------
// 512 blocks x 256 thr, block = (b, 8 rows). Softmax: wave w owns rows 2w,2w+1,
// lane covers cols {lane, lane+64}; shfl_xor allreduce (no barriers).
// Agg: thread = 2 rows (2ty,2ty+1) x 4 cols (4tx). do_pool: write pool partials.
__global__ __launch_bounds__(256) void k_attn(
    const float* __restrict__ h, const float* __restrict__ s1,
    const float* __restrict__ s2, const int* __restrict__ adj,
    float* __restrict__ x, float* __restrict__ gpart, int do_pool) {
    __shared__ float att_t[128][10];   // [col][row], stride 10: aligned float2, low conflict
    __shared__ float pool_red[4][256];
    int blk = blockIdx.x, b = blk >> 4, i0 = (blk & 15) << 3;
    int t = threadIdx.x, w = t >> 6, lane = t & 63;
    #pragma unroll
    for (int rr = 0; rr < 2; ++rr) {
        int r = 2 * w + rr, i = i0 + r;
        float sv = s1[b * 128 + i];
        int c0 = lane, c1 = lane + 64;
        float e0 = sv + s2[b * 128 + c0]; e0 = (e0 >= 0.f) ? e0 : 0.2f * e0;
        float e1 = sv + s2[b * 128 + c1]; e1 = (e1 >= 0.f) ? e1 : 0.2f * e1;
        const int* arow = adj + (size_t)(b * 128 + i) * 128;
        float v0 = (arow[c0] > 0) ? e0 : NEG_INF;
        float v1 = (arow[c1] > 0) ? e1 : NEG_INF;
        float m = fmaxf(v0, v1);
        #pragma unroll
        for (int off = 1; off < 64; off <<= 1) m = fmaxf(m, __shfl_xor(m, off, 64));
        float p0 = __expf(v0 - m), p1 = __expf(v1 - m);
        float s = p0 + p1;
        #pragma unroll
        for (int off = 1; off < 64; off <<= 1) s += __shfl_xor(s, off, 64);
        float inv = 1.0f / s;
        att_t[c0][r] = p0 * inv;
        att_t[c1][r] = p1 * inv;
    }
    __syncthreads();
    int tx = t & 63, ty = t >> 6;
    float acc0[4] = {0.f, 0.f, 0.f, 0.f}, acc1[4] = {0.f, 0.f, 0.f, 0.f};
    const float* hb = h + (size_t)b * 32768;
    #pragma unroll 4
    for (int j = 0; j < 128; ++j) {
        float4 hv = *(const float4*)&hb[j * 256 + 4 * tx];
        float2 ap = *(const float2*)&att_t[j][2 * ty];  // broadcast b64
        acc0[0] += ap.x * hv.x; acc0[1] += ap.x * hv.y;
        acc0[2] += ap.x * hv.z; acc0[3] += ap.x * hv.w;
        acc1[0] += ap.y * hv.x; acc1[1] += ap.y * hv.y;
        acc1[2] += ap.y * hv.z; acc1[3] += ap.y * hv.w;
    }
    if (!do_pool) {
        float4 o0 = {fmaxf(acc0[0],0.f), fmaxf(acc0[1],0.f), fmaxf(acc0[2],0.f), fmaxf(acc0[3],0.f)};
        float4 o1 = {fmaxf(acc1[0],0.f), fmaxf(acc1[1],0.f), fmaxf(acc1[2],0.f), fmaxf(acc1[3],0.f)};
        *(float4*)&x[(size_t)(b * 128 + i0 + 2 * ty)     * 256 + 4 * tx] = o0;
        *(float4*)&x[(size_t)(b * 128 + i0 + 2 * ty + 1) * 256 + 4 * tx] = o1;
    } else {
        float4 pr = {(fmaxf(acc0[0],0.f) + fmaxf(acc1[0],0.f)) * (1.f/128.f),
                     (fmaxf(acc0[1],0.f) + fmaxf(acc1[1],0.f)) * (1.f/128.f),
                     (fmaxf(acc0[2],0.f) + fmaxf(acc1[2],0.f)) * (1.f/128.f),
                     (fmaxf(acc0[3],0.f) + fmaxf(acc1[3],0.f)) * (1.f/128.f)};
        *(float4*)&pool_red[ty][4 * tx] = pr;
        __syncthreads();
        if (t < 64) {
            float4 r0 = ((const float4*)&pool_red[0][0])[t];
            float4 r1 = ((const float4*)&pool_red[1][0])[t];
            float4 r2 = ((const float4*)&pool_red[2][0])[t];
            float4 r3 = ((const float4*)&pool_red[3][0])[t];
            float4 o = {r0.x+r1.x+r2.x+r3.x, r0.y+r1.y+r2.y+r3.y,
                        r0.z+r1.z+r2.z+r3.z, r0.w+r1.w+r2.w+r3.w};
            *(float4*)&gpart[((size_t)b * 16 + (blk & 15)) * 256 + 4 * t] = o;
        }
    }
}

// ---------------- head: pool MLPs + concat + out MLP ------------------------
template <typename T>
__device__ __forceinline__ void head_body(
    int b, int t, const float* __restrict__ gpart,
    const T* scaf, const T* W_sc, const T* b_sc,
    const T* gp_w1, const T* gp_b1, const T* gp_w2, const T* gp_b2,
    const T* out_w1, const T* out_b1, const T* out_w2, const T* out_b2,
    float* gin_s, float* sproj, float* scaf_s,
    float* red1, float* red2, float* z1g, float* z1s,
    float* cvec, float* hdn, float* outv) {
    float g = 0.f;
    #pragma unroll
    for (int gg = 0; gg < 16; ++gg) g += gpart[((size_t)b * 16 + gg) * 256 + t];
    gin_s[t] = g;
    if (t < 20) scaf_s[t] = ldv(scaf, b * 20 + t);
    __syncthreads();
    {
        float sa = ldv(b_sc, t);
        #pragma unroll
        for (int k = 0; k < 20; ++k) sa += scaf_s[k] * ldv(W_sc, k * 256 + t);
        sproj[t] = sa;
    }
    __syncthreads();
    {
        int j = t & 127, khalf = t >> 7;
        int k0 = khalf * 128;
        float a1 = 0.f, a2 = 0.f;
        #pragma unroll 8
        for (int kk = 0; kk < 128; ++kk) {
            int k = k0 + kk;
            float wv = ldv(gp_w1, k * 128 + j);
            a1 += gin_s[k] * wv;
            a2 += sproj[k] * wv;
        }
        red1[t] = a1; red2[t] = a2;
    }
    __syncthreads();
    if (t < 128) {
        float bb = ldv(gp_b1, t);
        z1g[t] = fmaxf(bb + red1[t] + red1[t + 128], 0.f);
        z1s[t] = fmaxf(bb + red2[t] + red2[t + 128], 0.f);
    }
    __syncthreads();
    {
        int j = t & 63, q = t >> 6;
        int k0 = q * 32;
        float a1 = 0.f, a2 = 0.f;
        #pragma unroll
        for (int kk = 0; kk < 32; ++kk) {
            int k = k0 + kk;
            float wv = ldv(gp_w2, k * 64 + j);
            a1 += z1g[k] * wv;
            a2 += z1s[k] * wv;
        }
        red1[t] = a1; red2[t] = a2;
    }
    __syncthreads();
    if (t < 64) {
        float bb = ldv(gp_b2, t);
        cvec[t]      = fmaxf(bb + red1[t] + red1[t + 64] + red1[t + 128] + red1[t + 192], 0.f);
        cvec[64 + t] = fmaxf(bb + red2[t] + red2[t + 64] + red2[t + 128] + red2[t + 192], 0.f);
    }
    __syncthreads();
    {
        int j = t & 127, khalf = t >> 7;
        int k0 = khalf * 64;
        float a = 0.f;
        #pragma unroll 8
        for (int kk = 0; kk < 64; ++kk) {
            int k = k0 + kk;
            a += cvec[k] * ldv(out_w1, k * 128 + j);
        }
        red1[t] = a;
    }
    __syncthreads();
    if (t < 128) hdn[t] = fmaxf(ldv(out_b1, t) + red1[t] + red1[t + 128], 0.f);
    __syncthreads();
    if (t < 13) {
        float a = ldv(out_b2, t);
        #pragma unroll 8
        for (int k = 0; k < 128; ++k) a += hdn[k] * ldv(out_w2, k * 13 + t);
        outv[t] = a;
    }
}

__global__ __launch_bounds__(256) void k_head(
    const float* __restrict__ gpart, const void* __restrict__ scaf,
    const void* __restrict__ W_sc, const void* __restrict__ b_sc,
    const void* __restrict__ gp_w1, const void* __restrict__ gp_b1,
    const void* __restrict__ gp_w2, const void* __restrict__ gp_b2,
    const void* __restrict__ out_w1, const void* __restrict__ out_b1,
    const void* __restrict__ out_w2, const void* __restrict__ out_b2,
    void* __restrict__ out, const void* __restrict__ Wn) {
    int isbf = sniff(Wn);
    int b = blockIdx.x;
    int t = threadIdx.x;
    __shared__ float gin_s[256], sproj[256], scaf_s[20];
    __shared__ float red1[256], red2[256];
    __shared__ float z1g[128], z1s[128], cvec[128], hdn[128], outv[13];
    if (isbf) {
        head_body<__hip_bfloat16>(b, t, gpart,
            (const __hip_bfloat16*)scaf, (const __hip_bfloat16*)W_sc, (const __hip_bfloat16*)b_sc,
            (const __hip_bfloat16*)gp_w1, (const __hip_bfloat16*)gp_b1,
            (const __hip_bfloat16*)gp_w2, (const __hip_bfloat16*)gp_b2,
            (const __hip_bfloat16*)out_w1, (const __hip_bfloat16*)out_b1,
            (const __hip_bfloat16*)out_w2, (const __hip_bfloat16*)out_b2,
            gin_s, sproj, scaf_s, red1, red2, z1g, z1s, cvec, hdn, outv);
    } else {
        head_body<float>(b, t, gpart,
            (const float*)scaf, (const float*)W_sc, (const float*)b_sc,
            (const float*)gp_w1, (const float*)gp_b1,
            (const float*)gp_w2, (const float*)gp_b2,
            (const float*)out_w1, (const float*)out_b1,
            (const float*)out_w2, (const float*)out_b2,
            gin_s, sproj, scaf_s, red1, red2, z1g, z1s, cvec, hdn, outv);
    }
    __syncthreads();
    if (t < 13) {
        if (isbf) ((__hip_bfloat16*)out)[b * 13 + t] = __float2bfloat16(outv[t]);
        else      ((float*)out)[b * 13 + t] = outv[t];
    }
}

extern "C" void kernel_launch(void* const* d_in, const int* in_sizes, int n_in,
                              void* d_out, int out_size, void* d_ws, size_t ws_size,
                              hipStream_t stream) {
    (void)in_sizes; (void)n_in; (void)out_size; (void)ws_size;
    const void* nf     = d_in[0];
    const int*  adj    = (const int*)d_in[2];
    const void* scaf   = d_in[3];
    const void* W_node = d_in[4];
    const void* b_node = d_in[5];
    const void* gat_W  = d_in[6];
    const void* gat_a  = d_in[7];
    const void* W_sc   = d_in[8];
    const void* b_sc   = d_in[9];
    const void* gp_w1  = d_in[10];
    const void* gp_b1  = d_in[11];
    const void* gp_w2  = d_in[12];
    const void* gp_b2  = d_in[13];
    const void* out_w1 = d_in[14];
    const void* out_b1 = d_in[15];
    const void* out_w2 = d_in[16];
    const void* out_b2 = d_in[17];

    float* ws    = (float*)d_ws;
    float* x     = ws;                 // 1048576 floats
    float* h     = ws + 1048576;       // 1048576 floats
    float* s1    = ws + 2097152;       // 4096
    float* s2    = s1 + 4096;          // 4096
    float* gpart = s2 + 4096;          // 32*16*256 = 131072 floats

    for (int l = 0; l < 3; ++l) {
        k_gat_h<<<512, 256, 0, stream>>>(x, gat_W, gat_a, l,
                                         nf, W_node, b_node, (l == 0) ? 1 : 0,
                                         h, s1, s2);
        k_attn<<<512, 256, 0, stream>>>(h, s1, s2, adj, x, gpart, (l == 2) ? 1 : 0);
    }
    k_head<<<32, 256, 0, stream>>>(gpart, scaf, W_sc, b_sc, gp_w1, gp_b1, gp_w2, gp_b2,
                                   out_w1, out_b1, out_w2, out_b2, d_out, W_node);
}

// Round 5
// 258.699 us; speedup vs baseline: 1.1908x; 1.0288x over previous
//
#include <hip/hip_runtime.h>
#include <hip/hip_bf16.h>

#define NEG_INF -9.0e15f

__device__ __forceinline__ float b2f(__hip_bfloat16 v) { return __bfloat162float(v); }
__device__ __forceinline__ float ldv(const float* p, int i) { return p[i]; }
__device__ __forceinline__ float ldv(const __hip_bfloat16* p, int i) { return __bfloat162float(p[i]); }

// raw 8-element register buffers (16B bf16 / 32B f32)
template <typename T> struct Raw;
template <> struct Raw<__hip_bfloat16> { uint4 v; };
template <> struct Raw<float> { float4 a, b; };

__device__ __forceinline__ void ldraw(const __hip_bfloat16* p, Raw<__hip_bfloat16>& r) {
    r.v = *(const uint4*)p;
}
__device__ __forceinline__ void ldraw(const float* p, Raw<float>& r) {
    const float4* q = (const float4*)p; r.a = q[0]; r.b = q[1];
}
__device__ __forceinline__ void unpack8(const Raw<__hip_bfloat16>& r, float* f) {
    f[0]=__uint_as_float(r.v.x<<16); f[1]=__uint_as_float(r.v.x&0xffff0000u);
    f[2]=__uint_as_float(r.v.y<<16); f[3]=__uint_as_float(r.v.y&0xffff0000u);
    f[4]=__uint_as_float(r.v.z<<16); f[5]=__uint_as_float(r.v.z&0xffff0000u);
    f[6]=__uint_as_float(r.v.w<<16); f[7]=__uint_as_float(r.v.w&0xffff0000u);
}
__device__ __forceinline__ void unpack8(const Raw<float>& r, float* f) {
    f[0]=r.a.x; f[1]=r.a.y; f[2]=r.a.z; f[3]=r.a.w;
    f[4]=r.b.x; f[5]=r.b.y; f[6]=r.b.z; f[7]=r.b.w;
}
__device__ __forceinline__ void ld8f(const float* p, float* f) {
    Raw<float> r; ldraw(p, r); unpack8(r, f);
}
__device__ __forceinline__ void ld8f(const __hip_bfloat16* p, float* f) {
    Raw<__hip_bfloat16> r; ldraw(p, r); unpack8(r, f);
}

// wave-level dtype sniff (uniform per wave): bf16 weights -> sane exponents.
__device__ __forceinline__ int sniff(const void* wnode) {
    const unsigned short* w = (const unsigned short*)wnode;
    int lane = threadIdx.x & 63;
    unsigned short u = w[2 * lane];
    int e = (u >> 7) & 0xFF;
    unsigned long long m = __ballot(e >= 100 && e <= 140);
    return __popcll(m) >= 48;
}

// ---------------- gat_h: h = x @ W[l]; s1 = h@a1; s2 = h@a2 -----------------
// 512 blocks x 256 thr. Thread: row ty=t>>5, 8 cols 8*tx (tx=t&31).
// Register ping-pong W prefetch + per-block k-phase stagger (L2 channel spread).
template <typename T>
__device__ __forceinline__ void gat_h_body(
    int row0, int t, int bx, const T* __restrict__ Wl, const T* __restrict__ ga,
    const T* __restrict__ nf, const T* __restrict__ Wn, const T* __restrict__ bn,
    const float* __restrict__ x, int first,
    float* __restrict__ h, float* __restrict__ s1, float* __restrict__ s2,
    float (*xs)[256], float (*nfs)[80]) {
    int tx = t & 31, ty = t >> 5;
    if (first) {
        for (int idx = t; idx < 624; idx += 256) {
            int r = idx / 78, k = idx - r * 78;
            nfs[r][k] = ldv(nf, (row0 + r) * 78 + k);
        }
        __syncthreads();
        float acc[8];
        ld8f(bn + 8 * tx, acc);
        for (int k = 0; k < 78; ++k) {
            float xv = nfs[ty][k];
            float w8[8]; ld8f(Wn + k * 256 + 8 * tx, w8);
            #pragma unroll
            for (int c = 0; c < 8; ++c) acc[c] += xv * w8[c];
        }
        #pragma unroll
        for (int c = 0; c < 8; ++c) xs[ty][8 * tx + c] = acc[c];
        __syncthreads();
    } else {
        for (int f = t; f < 512; f += 256) {
            int r = f >> 6, pos = f & 63;
            ((float4*)&xs[r][0])[pos] = ((const float4*)&x[(size_t)(row0 + r) * 256])[pos];
        }
        __syncthreads();
    }

    const int ph = (bx & 63) << 2;          // k-phase, multiple of 4
    const T* Wp = Wl + 8 * tx;
    Raw<T> A[4], B[4];
    #pragma unroll
    for (int i = 0; i < 4; ++i) ldraw(Wp + ((i + ph) & 255) * 256, A[i]);
    float acc[8];
    #pragma unroll
    for (int c = 0; c < 8; ++c) acc[c] = 0.f;

    #pragma unroll 1
    for (int k0 = 0; k0 < 256; k0 += 8) {
        #pragma unroll
        for (int i = 0; i < 4; ++i) ldraw(Wp + ((k0 + 4 + i + ph) & 255) * 256, B[i]);
        {
            int ka = (k0 + ph) & 255;
            float4 xv = *(const float4*)&xs[ty][ka];
            float xc[4] = {xv.x, xv.y, xv.z, xv.w};
            #pragma unroll
            for (int i = 0; i < 4; ++i) {
                float w8[8]; unpack8(A[i], w8);
                #pragma unroll
                for (int c = 0; c < 8; ++c) acc[c] += xc[i] * w8[c];
            }
        }
        #pragma unroll
        for (int i = 0; i < 4; ++i) ldraw(Wp + ((k0 + 8 + i + ph) & 255) * 256, A[i]);
        {
            int kb = (k0 + 4 + ph) & 255;
            float4 xv = *(const float4*)&xs[ty][kb];
            float xc[4] = {xv.x, xv.y, xv.z, xv.w};
            #pragma unroll
            for (int i = 0; i < 4; ++i) {
                float w8[8]; unpack8(B[i], w8);
                #pragma unroll
                for (int c = 0; c < 8; ++c) acc[c] += xc[i] * w8[c];
            }
        }
    }

    // s1/s2 from register h (= x@(W@a) by associativity; ref computes h@a)
    float a1v[8], a2v[8];
    ld8f(ga + 8 * tx, a1v);
    ld8f(ga + 256 + 8 * tx, a2v);
    float d1 = 0.f, d2 = 0.f;
    #pragma unroll
    for (int c = 0; c < 8; ++c) { d1 += acc[c] * a1v[c]; d2 += acc[c] * a2v[c]; }
    #pragma unroll
    for (int off = 1; off < 32; off <<= 1) {
        d1 += __shfl_xor(d1, off, 64);
        d2 += __shfl_xor(d2, off, 64);
    }
    int row = row0 + ty;
    if (tx == 0) { s1[row] = d1; s2[row] = d2; }
    float4 h0 = {acc[0], acc[1], acc[2], acc[3]};
    float4 h1 = {acc[4], acc[5], acc[6], acc[7]};
    *(float4*)&h[(size_t)row * 256 + 8 * tx]     = h0;
    *(float4*)&h[(size_t)row * 256 + 8 * tx + 4] = h1;
}

__global__ __launch_bounds__(256, 2) void k_gat_h(
    const float* __restrict__ x, const void* __restrict__ gat_W,
    const void* __restrict__ gat_a, int layer,
    const void* __restrict__ nf, const void* __restrict__ Wn,
    const void* __restrict__ bn, int first,
    float* __restrict__ h, float* __restrict__ s1, float* __restrict__ s2) {
    __shared__ float xs[8][256];
    __shared__ float nfs[8][80];
    int row0 = blockIdx.x * 8;
    int t = threadIdx.x;
    if (sniff(Wn)) {
        gat_h_body<__hip_bfloat16>(row0, t, blockIdx.x,
            (const __hip_bfloat16*)gat_W + (size_t)layer * 65536,
            (const __hip_bfloat16*)gat_a + (size_t)layer * 512,
            (const __hip_bfloat16*)nf, (const __hip_bfloat16*)Wn,
            (const __hip_bfloat16*)bn, x, first, h, s1, s2, xs, nfs);
    } else {
        gat_h_body<float>(row0, t, blockIdx.x,
            (const float*)gat_W + (size_t)layer * 65536,
            (const float*)gat_a + (size_t)layer * 512,
            (const float*)nf, (const float*)Wn, (const float*)bn,
            x, first, h, s1, s2, xs, nfs);
    }
}

// ---------------- attn: softmax(mask(leaky(s1+s2))) @ h ---------------------
__global__ __launch_bounds__(256, 2) void k_attn(
    const float* __restrict__ h, const float* __restrict__ s1,
    const float* __restrict__ s2, const int* __restrict__ adj,
    float* __restrict__ x, float* __restrict__ gpart, int do_pool) {
    __shared__ float att_t[128][10];   // [col][row], stride 10
    __shared__ float pool_red[4][256];
    int blk = blockIdx.x, b = blk >> 4, i0 = (blk & 15) << 3;
    int t = threadIdx.x, w = t >> 6, lane = t & 63;
    // ---- softmax: wave w owns rows 2w, 2w+1; all loads issued up-front ----
    {
        int c0 = lane, c1 = lane + 64;
        int ir0 = i0 + 2 * w, ir1 = ir0 + 1;
        const int* a0 = adj + (size_t)(b * 128 + ir0) * 128;
        const int* a1 = adj + (size_t)(b * 128 + ir1) * 128;
        int m00 = a0[c0], m01 = a0[c1], m10 = a1[c0], m11 = a1[c1];
        float sv0 = s1[b * 128 + ir0], sv1 = s1[b * 128 + ir1];
        float t0 = s2[b * 128 + c0],   t1 = s2[b * 128 + c1];
        float e00 = sv0 + t0; e00 = (e00 >= 0.f) ? e00 : 0.2f * e00;
        float e01 = sv0 + t1; e01 = (e01 >= 0.f) ? e01 : 0.2f * e01;
        float e10 = sv1 + t0; e10 = (e10 >= 0.f) ? e10 : 0.2f * e10;
        float e11 = sv1 + t1; e11 = (e11 >= 0.f) ? e11 : 0.2f * e11;
        float v00 = (m00 > 0) ? e00 : NEG_INF;
        float v01 = (m01 > 0) ? e01 : NEG_INF;
        float v10 = (m10 > 0) ? e10 : NEG_INF;
        float v11 = (m11 > 0) ? e11 : NEG_INF;
        float mx0 = fmaxf(v00, v01), mx1 = fmaxf(v10, v11);
        #pragma unroll
        for (int off = 1; off < 64; off <<= 1) {
            mx0 = fmaxf(mx0, __shfl_xor(mx0, off, 64));
            mx1 = fmaxf(mx1, __shfl_xor(mx1, off, 64));
        }
        float p00 = __expf(v00 - mx0), p01 = __expf(v01 - mx0);
        float p10 = __expf(v10 - mx1), p11 = __expf(v11 - mx1);
        float s0 = p00 + p01, ss1 = p10 + p11;
        #pragma unroll
        for (int off = 1; off < 64; off <<= 1) {
            s0  += __shfl_xor(s0, off, 64);
            ss1 += __shfl_xor(ss1, off, 64);
        }
        float inv0 = 1.0f / s0, inv1 = 1.0f / ss1;
        att_t[c0][2 * w]     = p00 * inv0;
        att_t[c1][2 * w]     = p01 * inv0;
        att_t[c0][2 * w + 1] = p10 * inv1;
        att_t[c1][2 * w + 1] = p11 * inv1;
    }
    __syncthreads();
    // ---- aggregation: thread = rows {2ty,2ty+1} x cols 4*tx; pipelined ----
    int tx = t & 63, ty = t >> 6;
    const int ph = (blk & 15) << 3;     // j-phase, multiple of 8
    const float* hp = h + (size_t)b * 32768 + 4 * tx;
    float4 A[4], B[4];
    #pragma unroll
    for (int i = 0; i < 4; ++i) A[i] = *(const float4*)&hp[((i + ph) & 127) * 256];
    float acc0[4] = {0.f, 0.f, 0.f, 0.f}, acc1[4] = {0.f, 0.f, 0.f, 0.f};
    #pragma unroll 1
    for (int j0 = 0; j0 < 128; j0 += 8) {
        #pragma unroll
        for (int i = 0; i < 4; ++i) B[i] = *(const float4*)&hp[((j0 + 4 + i + ph) & 127) * 256];
        #pragma unroll
        for (int i = 0; i < 4; ++i) {
            float2 ap = *(const float2*)&att_t[(j0 + i + ph) & 127][2 * ty];
            float4 hv = A[i];
            acc0[0] += ap.x * hv.x; acc0[1] += ap.x * hv.y;
            acc0[2] += ap.x * hv.z; acc0[3] += ap.x * hv.w;
            acc1[0] += ap.y * hv.x; acc1[1] += ap.y * hv.y;
            acc1[2] += ap.y * hv.z; acc1[3] += ap.y * hv.w;
        }
        #pragma unroll
        for (int i = 0; i < 4; ++i) A[i] = *(const float4*)&hp[((j0 + 8 + i + ph) & 127) * 256];
        #pragma unroll
        for (int i = 0; i < 4; ++i) {
            float2 ap = *(const float2*)&att_t[(j0 + 4 + i + ph) & 127][2 * ty];
            float4 hv = B[i];
            acc0[0] += ap.x * hv.x; acc0[1] += ap.x * hv.y;
            acc0[2] += ap.x * hv.z; acc0[3] += ap.x * hv.w;
            acc1[0] += ap.y * hv.x; acc1[1] += ap.y * hv.y;
            acc1[2] += ap.y * hv.z; acc1[3] += ap.y * hv.w;
        }
    }
    if (!do_pool) {
        float4 o0 = {fmaxf(acc0[0],0.f), fmaxf(acc0[1],0.f), fmaxf(acc0[2],0.f), fmaxf(acc0[3],0.f)};
        float4 o1 = {fmaxf(acc1[0],0.f), fmaxf(acc1[1],0.f), fmaxf(acc1[2],0.f), fmaxf(acc1[3],0.f)};
        *(float4*)&x[(size_t)(b * 128 + i0 + 2 * ty)     * 256 + 4 * tx] = o0;
        *(float4*)&x[(size_t)(b * 128 + i0 + 2 * ty + 1) * 256 + 4 * tx] = o1;
    } else {
        float4 pr = {(fmaxf(acc0[0],0.f) + fmaxf(acc1[0],0.f)) * (1.f/128.f),
                     (fmaxf(acc0[1],0.f) + fmaxf(acc1[1],0.f)) * (1.f/128.f),
                     (fmaxf(acc0[2],0.f) + fmaxf(acc1[2],0.f)) * (1.f/128.f),
                     (fmaxf(acc0[3],0.f) + fmaxf(acc1[3],0.f)) * (1.f/128.f)};
        *(float4*)&pool_red[ty][4 * tx] = pr;
        __syncthreads();
        if (t < 64) {
            float4 r0 = ((const float4*)&pool_red[0][0])[t];
            float4 r1 = ((const float4*)&pool_red[1][0])[t];
            float4 r2 = ((const float4*)&pool_red[2][0])[t];
            float4 r3 = ((const float4*)&pool_red[3][0])[t];
            float4 o = {r0.x+r1.x+r2.x+r3.x, r0.y+r1.y+r2.y+r3.y,
                        r0.z+r1.z+r2.z+r3.z, r0.w+r1.w+r2.w+r3.w};
            *(float4*)&gpart[((size_t)b * 16 + (blk & 15)) * 256 + 4 * t] = o;
        }
    }
}

// ---------------- head: pool MLPs + concat + out MLP ------------------------
template <typename T>
__device__ __forceinline__ void head_body(
    int b, int t, const float* __restrict__ gpart,
    const T* scaf, const T* W_sc, const T* b_sc,
    const T* gp_w1, const T* gp_b1, const T* gp_w2, const T* gp_b2,
    const T* out_w1, const T* out_b1, const T* out_w2, const T* out_b2,
    float* gin_s, float* sproj, float* scaf_s,
    float* red1, float* red2, float* z1g, float* z1s,
    float* cvec, float* hdn, float* outv) {
    float g = 0.f;
    #pragma unroll
    for (int gg = 0; gg < 16; ++gg) g += gpart[((size_t)b * 16 + gg) * 256 + t];
    gin_s[t] = g;
    if (t < 20) scaf_s[t] = ldv(scaf, b * 20 + t);
    __syncthreads();
    {
        float sa = ldv(b_sc, t);
        #pragma unroll
        for (int k = 0; k < 20; ++k) sa += scaf_s[k] * ldv(W_sc, k * 256 + t);
        sproj[t] = sa;
    }
    __syncthreads();
    {
        int j = t & 127, khalf = t >> 7;
        int k0 = khalf * 128;
        float a1 = 0.f, a2 = 0.f;
        #pragma unroll 16
        for (int kk = 0; kk < 128; ++kk) {
            int k = k0 + kk;
            float wv = ldv(gp_w1, k * 128 + j);
            a1 += gin_s[k] * wv;
            a2 += sproj[k] * wv;
        }
        red1[t] = a1; red2[t] = a2;
    }
    __syncthreads();
    if (t < 128) {
        float bb = ldv(gp_b1, t);
        z1g[t] = fmaxf(bb + red1[t] + red1[t + 128], 0.f);
        z1s[t] = fmaxf(bb + red2[t] + red2[t + 128], 0.f);
    }
    __syncthreads();
    {
        int j = t & 63, q = t >> 6;
        int k0 = q * 32;
        float a1 = 0.f, a2 = 0.f;
        #pragma unroll
        for (int kk = 0; kk < 32; ++kk) {
            int k = k0 + kk;
            float wv = ldv(gp_w2, k * 64 + j);
            a1 += z1g[k] * wv;
            a2 += z1s[k] * wv;
        }
        red1[t] = a1; red2[t] = a2;
    }
    __syncthreads();
    if (t < 64) {
        float bb = ldv(gp_b2, t);
        cvec[t]      = fmaxf(bb + red1[t] + red1[t + 64] + red1[t + 128] + red1[t + 192], 0.f);
        cvec[64 + t] = fmaxf(bb + red2[t] + red2[t + 64] + red2[t + 128] + red2[t + 192], 0.f);
    }
    __syncthreads();
    {
        int j = t & 127, khalf = t >> 7;
        int k0 = khalf * 64;
        float a = 0.f;
        #pragma unroll 16
        for (int kk = 0; kk < 64; ++kk) {
            int k = k0 + kk;
            a += cvec[k] * ldv(out_w1, k * 128 + j);
        }
        red1[t] = a;
    }
    __syncthreads();
    if (t < 128) hdn[t] = fmaxf(ldv(out_b1, t) + red1[t] + red1[t + 128], 0.f);
    __syncthreads();
    if (t < 13) {
        float a = ldv(out_b2, t);
        #pragma unroll 16
        for (int k = 0; k < 128; ++k) a += hdn[k] * ldv(out_w2, k * 13 + t);
        outv[t] = a;
    }
}

__global__ __launch_bounds__(256) void k_head(
    const float* __restrict__ gpart, const void* __restrict__ scaf,
    const void* __restrict__ W_sc, const void* __restrict__ b_sc,
    const void* __restrict__ gp_w1, const void* __restrict__ gp_b1,
    const void* __restrict__ gp_w2, const void* __restrict__ gp_b2,
    const void* __restrict__ out_w1, const void* __restrict__ out_b1,
    const void* __restrict__ out_w2, const void* __restrict__ out_b2,
    void* __restrict__ out, const void* __restrict__ Wn) {
    int isbf = sniff(Wn);
    int b = blockIdx.x;
    int t = threadIdx.x;
    __shared__ float gin_s[256], sproj[256], scaf_s[20];
    __shared__ float red1[256], red2[256];
    __shared__ float z1g[128], z1s[128], cvec[128], hdn[128], outv[13];
    if (isbf) {
        head_body<__hip_bfloat16>(b, t, gpart,
            (const __hip_bfloat16*)scaf, (const __hip_bfloat16*)W_sc, (const __hip_bfloat16*)b_sc,
            (const __hip_bfloat16*)gp_w1, (const __hip_bfloat16*)gp_b1,
            (const __hip_bfloat16*)gp_w2, (const __hip_bfloat16*)gp_b2,
            (const __hip_bfloat16*)out_w1, (const __hip_bfloat16*)out_b1,
            (const __hip_bfloat16*)out_w2, (const __hip_bfloat16*)out_b2,
            gin_s, sproj, scaf_s, red1, red2, z1g, z1s, cvec, hdn, outv);
    } else {
        head_body<float>(b, t, gpart,
            (const float*)scaf, (const float*)W_sc, (const float*)b_sc,
            (const float*)gp_w1, (const float*)gp_b1,
            (const float*)gp_w2, (const float*)gp_b2,
            (const float*)out_w1, (const float*)out_b1,
            (const float*)out_w2, (const float*)out_b2,
            gin_s, sproj, scaf_s, red1, red2, z1g, z1s, cvec, hdn, outv);
    }
    __syncthreads();
    if (t < 13) {
        if (isbf) ((__hip_bfloat16*)out)[b * 13 + t] = __float2bfloat16(outv[t]);
        else      ((float*)out)[b * 13 + t] = outv[t];
    }
}

extern "C" void kernel_launch(void* const* d_in, const int* in_sizes, int n_in,
                              void* d_out, int out_size, void* d_ws, size_t ws_size,
                              hipStream_t stream) {
    (void)in_sizes; (void)n_in; (void)out_size; (void)ws_size;
    const void* nf     = d_in[0];
    const int*  adj    = (const int*)d_in[2];
    const void* scaf   = d_in[3];
    const void* W_node = d_in[4];
    const void* b_node = d_in[5];
    const void* gat_W  = d_in[6];
    const void* gat_a  = d_in[7];
    const void* W_sc   = d_in[8];
    const void* b_sc   = d_in[9];
    const void* gp_w1  = d_in[10];
    const void* gp_b1  = d_in[11];
    const void* gp_w2  = d_in[12];
    const void* gp_b2  = d_in[13];
    const void* out_w1 = d_in[14];
    const void* out_b1 = d_in[15];
    const void* out_w2 = d_in[16];
    const void* out_b2 = d_in[17];

    float* ws    = (float*)d_ws;
    float* x     = ws;                 // 1048576 floats
    float* h     = ws + 1048576;       // 1048576 floats
    float* s1    = ws + 2097152;       // 4096
    float* s2    = s1 + 4096;          // 4096
    float* gpart = s2 + 4096;          // 32*16*256 = 131072 floats

    for (int l = 0; l < 3; ++l) {
        k_gat_h<<<512, 256, 0, stream>>>(x, gat_W, gat_a, l,
                                         nf, W_node, b_node, (l == 0) ? 1 : 0,
                                         h, s1, s2);
        k_attn<<<512, 256, 0, stream>>>(h, s1, s2, adj, x, gpart, (l == 2) ? 1 : 0);
    }
    k_head<<<32, 256, 0, stream>>>(gpart, scaf, W_sc, b_sc, gp_w1, gp_b1, gp_w2, gp_b2,
                                   out_w1, out_b1, out_w2, out_b2, d_out, W_node);
}

// Round 6
// 236.730 us; speedup vs baseline: 1.3014x; 1.0928x over previous
//
#include <hip/hip_runtime.h>
#include <hip/hip_bf16.h>

#define NEG_INF -9.0e15f

__device__ __forceinline__ float b2f(__hip_bfloat16 v) { return __bfloat162float(v); }
__device__ __forceinline__ float ldv(const float* p, int i) { return p[i]; }
__device__ __forceinline__ float ldv(const __hip_bfloat16* p, int i) { return __bfloat162float(p[i]); }

__device__ __forceinline__ void unpack8u(uint4 r, float* f) {
    f[0]=__uint_as_float(r.x<<16); f[1]=__uint_as_float(r.x&0xffff0000u);
    f[2]=__uint_as_float(r.y<<16); f[3]=__uint_as_float(r.y&0xffff0000u);
    f[4]=__uint_as_float(r.z<<16); f[5]=__uint_as_float(r.z&0xffff0000u);
    f[6]=__uint_as_float(r.w<<16); f[7]=__uint_as_float(r.w&0xffff0000u);
}
__device__ __forceinline__ void ld8f(const float* p, float* f) {
    const float4* q = (const float4*)p;
    float4 a = q[0], b = q[1];
    f[0]=a.x; f[1]=a.y; f[2]=a.z; f[3]=a.w; f[4]=b.x; f[5]=b.y; f[6]=b.z; f[7]=b.w;
}
__device__ __forceinline__ void ld8f(const __hip_bfloat16* p, float* f) {
    unpack8u(*(const uint4*)p, f);
}

// async global->LDS, 16B per lane (dest = wave-uniform base + lane*16)
__device__ __forceinline__ void async16(const void* g, void* l) {
    __builtin_amdgcn_global_load_lds(
        (__attribute__((address_space(1))) void*)(g),
        (__attribute__((address_space(3))) void*)(l), 16, 0, 0);
}

// wave-level dtype sniff (uniform per wave): bf16 weights -> sane exponents.
__device__ __forceinline__ int sniff(const void* wnode) {
    const unsigned short* w = (const unsigned short*)wnode;
    int lane = threadIdx.x & 63;
    unsigned short u = w[2 * lane];
    int e = (u >> 7) & 0xFF;
    unsigned long long m = __ballot(e >= 100 && e <= 140);
    return __popcll(m) >= 48;
}

// shared epilogue: s1/s2 via half-wave reduction + h stores
template <typename T>
__device__ __forceinline__ void gat_epilogue(
    const T* __restrict__ ga, int tx, int ty, int row0,
    const float* acc0, const float* acc1,
    float* __restrict__ h, float* __restrict__ s1, float* __restrict__ s2) {
    float a1v[8], a2v[8];
    ld8f(ga + 8 * tx, a1v);
    ld8f(ga + 256 + 8 * tx, a2v);
    float d10 = 0.f, d20 = 0.f, d11 = 0.f, d21 = 0.f;
    #pragma unroll
    for (int j = 0; j < 8; ++j) {
        d10 += acc0[j] * a1v[j]; d20 += acc0[j] * a2v[j];
        d11 += acc1[j] * a1v[j]; d21 += acc1[j] * a2v[j];
    }
    #pragma unroll
    for (int off = 1; off < 32; off <<= 1) {   // reduce within each 32-lane half
        d10 += __shfl_xor(d10, off, 64); d20 += __shfl_xor(d20, off, 64);
        d11 += __shfl_xor(d11, off, 64); d21 += __shfl_xor(d21, off, 64);
    }
    if (tx == 0) {                              // lanes 0 and 32 of each wave
        s1[row0 + ty] = d10;     s2[row0 + ty] = d20;
        s1[row0 + ty + 8] = d11; s2[row0 + ty + 8] = d21;
    }
    float4 o00 = {acc0[0], acc0[1], acc0[2], acc0[3]};
    float4 o01 = {acc0[4], acc0[5], acc0[6], acc0[7]};
    float4 o10 = {acc1[0], acc1[1], acc1[2], acc1[3]};
    float4 o11 = {acc1[4], acc1[5], acc1[6], acc1[7]};
    *(float4*)&h[(size_t)(row0 + ty) * 256 + 8 * tx]         = o00;
    *(float4*)&h[(size_t)(row0 + ty) * 256 + 8 * tx + 4]     = o01;
    *(float4*)&h[(size_t)(row0 + ty + 8) * 256 + 8 * tx]     = o10;
    *(float4*)&h[(size_t)(row0 + ty + 8) * 256 + 8 * tx + 4] = o11;
}

// ---------------- gat_h: h = x @ W[l]; s1 = h@a1; s2 = h@a2 -----------------
// 256 blocks x 256 thr. Block = 16 rows x 256 cols. Thread: rows {ty, ty+8},
// cols 8tx..8tx+7. bf16 path: W staged via global_load_lds, 32-k chunks, dbuf.
__global__ __launch_bounds__(256) void k_gat_h(
    const float* __restrict__ x, const void* __restrict__ gat_W,
    const void* __restrict__ gat_a, int layer,
    const void* __restrict__ nf, const void* __restrict__ Wn,
    const void* __restrict__ bn, int first,
    float* __restrict__ h, float* __restrict__ s1, float* __restrict__ s2) {
    __shared__ float xs[16][256];
    __shared__ float nfs[16][80];
    __shared__ __align__(16) unsigned short Wbuf[2][32 * 256];   // 2 x 16 KB
    const int t = threadIdx.x;
    const int row0 = blockIdx.x * 16;
    const int tx = t & 31, ty = t >> 5;
    const int isbf = sniff(Wn);

    if (isbf) {
        const __hip_bfloat16* Wl = (const __hip_bfloat16*)gat_W + (size_t)layer * 65536;
        const __hip_bfloat16* ga = (const __hip_bfloat16*)gat_a + (size_t)layer * 512;
        // stage chunk 0 immediately (overlaps xs preparation)
        {
            const char* g = (const char*)Wl;
            char* lb = (char*)&Wbuf[0][0];
            #pragma unroll
            for (int i = 0; i < 4; ++i)
                async16(g + i * 4096 + t * 16, lb + i * 4096 + t * 16);
        }
        if (first) {
            for (int idx = t; idx < 16 * 78; idx += 256) {
                int r = idx / 78, k = idx - r * 78;
                nfs[r][k] = b2f(((const __hip_bfloat16*)nf)[(row0 + r) * 78 + k]);
            }
            __syncthreads();
            const __hip_bfloat16* Wnb = (const __hip_bfloat16*)Wn;
            float p0[8], p1[8];
            ld8f((const __hip_bfloat16*)bn + 8 * tx, p0);
            #pragma unroll
            for (int j = 0; j < 8; ++j) p1[j] = p0[j];
            for (int k = 0; k < 78; ++k) {
                float w8[8]; ld8f(Wnb + k * 256 + 8 * tx, w8);
                float xv0 = nfs[ty][k], xv1 = nfs[ty + 8][k];
                #pragma unroll
                for (int j = 0; j < 8; ++j) {
                    p0[j] += xv0 * w8[j];
                    p1[j] += xv1 * w8[j];
                }
            }
            #pragma unroll
            for (int j = 0; j < 8; ++j) {
                xs[ty][8 * tx + j] = p0[j];
                xs[ty + 8][8 * tx + j] = p1[j];
            }
            __syncthreads();
        } else {
            #pragma unroll
            for (int i = 0; i < 4; ++i) {
                int idx = t + 256 * i;             // float4 index into 16x256
                int r = idx >> 6, c4 = idx & 63;
                ((float4*)&xs[r][0])[c4] = ((const float4*)&x[(size_t)(row0 + r) * 256])[c4];
            }
            __syncthreads();
        }
        float acc0[8], acc1[8];
        #pragma unroll
        for (int j = 0; j < 8; ++j) { acc0[j] = 0.f; acc1[j] = 0.f; }
        for (int c = 0; c < 8; ++c) {
            if (c < 7) {
                const char* g = (const char*)Wl + (c + 1) * 16384;
                char* lb = (char*)&Wbuf[(c + 1) & 1][0];
                #pragma unroll
                for (int i = 0; i < 4; ++i)
                    async16(g + i * 4096 + t * 16, lb + i * 4096 + t * 16);
            }
            const unsigned short* Wc = &Wbuf[c & 1][0];
            const int kb = c * 32;
            #pragma unroll 2
            for (int k0 = 0; k0 < 32; k0 += 4) {
                float4 xa = *(const float4*)&xs[ty][kb + k0];
                float4 xb = *(const float4*)&xs[ty + 8][kb + k0];
                float xav[4] = {xa.x, xa.y, xa.z, xa.w};
                float xbv[4] = {xb.x, xb.y, xb.z, xb.w};
                #pragma unroll
                for (int kk = 0; kk < 4; ++kk) {
                    uint4 wv = *(const uint4*)&Wc[(k0 + kk) * 256 + 8 * tx];
                    float w8[8]; unpack8u(wv, w8);
                    #pragma unroll
                    for (int j = 0; j < 8; ++j) {
                        acc0[j] += xav[kk] * w8[j];
                        acc1[j] += xbv[kk] * w8[j];
                    }
                }
            }
            __syncthreads();   // drains stage(c+1) + releases Wbuf[c&1]
        }
        gat_epilogue<__hip_bfloat16>(ga, tx, ty, row0, acc0, acc1, h, s1, s2);
    } else {
        // f32 fallback: correct, unoptimized
        const float* Wl = (const float*)gat_W + (size_t)layer * 65536;
        const float* ga = (const float*)gat_a + (size_t)layer * 512;
        if (first) {
            for (int idx = t; idx < 16 * 78; idx += 256) {
                int r = idx / 78, k = idx - r * 78;
                nfs[r][k] = ((const float*)nf)[(row0 + r) * 78 + k];
            }
            __syncthreads();
            float p0[8], p1[8];
            ld8f((const float*)bn + 8 * tx, p0);
            #pragma unroll
            for (int j = 0; j < 8; ++j) p1[j] = p0[j];
            for (int k = 0; k < 78; ++k) {
                float w8[8]; ld8f((const float*)Wn + k * 256 + 8 * tx, w8);
                float xv0 = nfs[ty][k], xv1 = nfs[ty + 8][k];
                #pragma unroll
                for (int j = 0; j < 8; ++j) { p0[j] += xv0 * w8[j]; p1[j] += xv1 * w8[j]; }
            }
            #pragma unroll
            for (int j = 0; j < 8; ++j) {
                xs[ty][8 * tx + j] = p0[j];
                xs[ty + 8][8 * tx + j] = p1[j];
            }
            __syncthreads();
        } else {
            #pragma unroll
            for (int i = 0; i < 4; ++i) {
                int idx = t + 256 * i;
                int r = idx >> 6, c4 = idx & 63;
                ((float4*)&xs[r][0])[c4] = ((const float4*)&x[(size_t)(row0 + r) * 256])[c4];
            }
            __syncthreads();
        }
        float acc0[8], acc1[8];
        #pragma unroll
        for (int j = 0; j < 8; ++j) { acc0[j] = 0.f; acc1[j] = 0.f; }
        for (int k = 0; k < 256; ++k) {
            float w8[8]; ld8f(Wl + k * 256 + 8 * tx, w8);
            float xv0 = xs[ty][k], xv1 = xs[ty + 8][k];
            #pragma unroll
            for (int j = 0; j < 8; ++j) { acc0[j] += xv0 * w8[j]; acc1[j] += xv1 * w8[j]; }
        }
        gat_epilogue<float>(ga, tx, ty, row0, acc0, acc1, h, s1, s2);
    }
}

// ---------------- attn: softmax(mask(leaky(s1+s2))) @ h ---------------------
// 512 blocks x 256 thr, block = (b, 8 rows). h staged via global_load_lds in
// 32-row f32 chunks (dbuf). Softmax: wave w owns rows 2w,2w+1 (shfl allreduce).
__global__ __launch_bounds__(256) void k_attn(
    const float* __restrict__ h, const float* __restrict__ s1,
    const float* __restrict__ s2, const int* __restrict__ adj,
    float* __restrict__ x, float* __restrict__ gpart, int do_pool) {
    __shared__ float att_t[128][10];                 // [col][row], stride 10
    __shared__ __align__(16) float hbuf[2][32 * 256]; // 2 x 32 KB
    __shared__ float pool_red[4][256];
    int blk = blockIdx.x, b = blk >> 4, i0 = (blk & 15) << 3;
    int t = threadIdx.x, w = t >> 6, lane = t & 63;
    const char* hbytes = (const char*)(h + (size_t)b * 32768);
    // stage chunk 0 of h (j rows 0..31) — overlaps softmax
    {
        char* lb = (char*)&hbuf[0][0];
        #pragma unroll
        for (int i = 0; i < 8; ++i)
            async16(hbytes + i * 4096 + t * 16, lb + i * 4096 + t * 16);
    }
    // ---- softmax ----
    {
        int c0 = lane, c1 = lane + 64;
        int ir0 = i0 + 2 * w, ir1 = ir0 + 1;
        const int* a0 = adj + (size_t)(b * 128 + ir0) * 128;
        const int* a1 = adj + (size_t)(b * 128 + ir1) * 128;
        int m00 = a0[c0], m01 = a0[c1], m10 = a1[c0], m11 = a1[c1];
        float sv0 = s1[b * 128 + ir0], sv1 = s1[b * 128 + ir1];
        float t0 = s2[b * 128 + c0],   t1 = s2[b * 128 + c1];
        float e00 = sv0 + t0; e00 = (e00 >= 0.f) ? e00 : 0.2f * e00;
        float e01 = sv0 + t1; e01 = (e01 >= 0.f) ? e01 : 0.2f * e01;
        float e10 = sv1 + t0; e10 = (e10 >= 0.f) ? e10 : 0.2f * e10;
        float e11 = sv1 + t1; e11 = (e11 >= 0.f) ? e11 : 0.2f * e11;
        float v00 = (m00 > 0) ? e00 : NEG_INF;
        float v01 = (m01 > 0) ? e01 : NEG_INF;
        float v10 = (m10 > 0) ? e10 : NEG_INF;
        float v11 = (m11 > 0) ? e11 : NEG_INF;
        float mx0 = fmaxf(v00, v01), mx1 = fmaxf(v10, v11);
        #pragma unroll
        for (int off = 1; off < 64; off <<= 1) {
            mx0 = fmaxf(mx0, __shfl_xor(mx0, off, 64));
            mx1 = fmaxf(mx1, __shfl_xor(mx1, off, 64));
        }
        float p00 = __expf(v00 - mx0), p01 = __expf(v01 - mx0);
        float p10 = __expf(v10 - mx1), p11 = __expf(v11 - mx1);
        float s0 = p00 + p01, ss1 = p10 + p11;
        #pragma unroll
        for (int off = 1; off < 64; off <<= 1) {
            s0  += __shfl_xor(s0, off, 64);
            ss1 += __shfl_xor(ss1, off, 64);
        }
        float inv0 = 1.0f / s0, inv1 = 1.0f / ss1;
        att_t[c0][2 * w]     = p00 * inv0;
        att_t[c1][2 * w]     = p01 * inv0;
        att_t[c0][2 * w + 1] = p10 * inv1;
        att_t[c1][2 * w + 1] = p11 * inv1;
    }
    __syncthreads();   // att_t ready + hbuf[0] staged
    // ---- aggregation: thread = rows {2ty,2ty+1} x cols 4tx, chunked LDS h ----
    int tx = t & 63, ty = t >> 6;
    float acc0[4] = {0.f, 0.f, 0.f, 0.f}, acc1[4] = {0.f, 0.f, 0.f, 0.f};
    for (int c = 0; c < 4; ++c) {
        if (c < 3) {
            char* lb = (char*)&hbuf[(c + 1) & 1][0];
            const char* g = hbytes + (c + 1) * 32768;
            #pragma unroll
            for (int i = 0; i < 8; ++i)
                async16(g + i * 4096 + t * 16, lb + i * 4096 + t * 16);
        }
        const float* hc = &hbuf[c & 1][0];
        #pragma unroll 4
        for (int jj = 0; jj < 32; ++jj) {
            float4 hv = *(const float4*)&hc[jj * 256 + 4 * tx];
            float2 ap = *(const float2*)&att_t[c * 32 + jj][2 * ty];
            acc0[0] += ap.x * hv.x; acc0[1] += ap.x * hv.y;
            acc0[2] += ap.x * hv.z; acc0[3] += ap.x * hv.w;
            acc1[0] += ap.y * hv.x; acc1[1] += ap.y * hv.y;
            acc1[2] += ap.y * hv.z; acc1[3] += ap.y * hv.w;
        }
        __syncthreads();
    }
    if (!do_pool) {
        float4 o0 = {fmaxf(acc0[0],0.f), fmaxf(acc0[1],0.f), fmaxf(acc0[2],0.f), fmaxf(acc0[3],0.f)};
        float4 o1 = {fmaxf(acc1[0],0.f), fmaxf(acc1[1],0.f), fmaxf(acc1[2],0.f), fmaxf(acc1[3],0.f)};
        *(float4*)&x[(size_t)(b * 128 + i0 + 2 * ty)     * 256 + 4 * tx] = o0;
        *(float4*)&x[(size_t)(b * 128 + i0 + 2 * ty + 1) * 256 + 4 * tx] = o1;
    } else {
        float4 pr = {(fmaxf(acc0[0],0.f) + fmaxf(acc1[0],0.f)) * (1.f/128.f),
                     (fmaxf(acc0[1],0.f) + fmaxf(acc1[1],0.f)) * (1.f/128.f),
                     (fmaxf(acc0[2],0.f) + fmaxf(acc1[2],0.f)) * (1.f/128.f),
                     (fmaxf(acc0[3],0.f) + fmaxf(acc1[3],0.f)) * (1.f/128.f)};
        *(float4*)&pool_red[ty][4 * tx] = pr;
        __syncthreads();
        if (t < 64) {
            float4 r0 = ((const float4*)&pool_red[0][0])[t];
            float4 r1 = ((const float4*)&pool_red[1][0])[t];
            float4 r2 = ((const float4*)&pool_red[2][0])[t];
            float4 r3 = ((const float4*)&pool_red[3][0])[t];
            float4 o = {r0.x+r1.x+r2.x+r3.x, r0.y+r1.y+r2.y+r3.y,
                        r0.z+r1.z+r2.z+r3.z, r0.w+r1.w+r2.w+r3.w};
            *(float4*)&gpart[((size_t)b * 16 + (blk & 15)) * 256 + 4 * t] = o;
        }
    }
}

// ---------------- head: pool MLPs + concat + out MLP ------------------------
template <typename T>
__device__ __forceinline__ void head_body(
    int b, int t, const float* __restrict__ gpart,
    const T* scaf, const T* W_sc, const T* b_sc,
    const T* gp_w1, const T* gp_b1, const T* gp_w2, const T* gp_b2,
    const T* out_w1, const T* out_b1, const T* out_w2, const T* out_b2,
    float* gin_s, float* sproj, float* scaf_s,
    float* red1, float* red2, float* z1g, float* z1s,
    float* cvec, float* hdn, float* outv) {
    float g = 0.f;
    #pragma unroll
    for (int gg = 0; gg < 16; ++gg) g += gpart[((size_t)b * 16 + gg) * 256 + t];
    gin_s[t] = g;
    if (t < 20) scaf_s[t] = ldv(scaf, b * 20 + t);
    __syncthreads();
    {
        float sa = ldv(b_sc, t);
        #pragma unroll
        for (int k = 0; k < 20; ++k) sa += scaf_s[k] * ldv(W_sc, k * 256 + t);
        sproj[t] = sa;
    }
    __syncthreads();
    {
        int j = t & 127, khalf = t >> 7;
        int k0 = khalf * 128;
        float a1 = 0.f, a2 = 0.f;
        #pragma unroll 16
        for (int kk = 0; kk < 128; ++kk) {
            int k = k0 + kk;
            float wv = ldv(gp_w1, k * 128 + j);
            a1 += gin_s[k] * wv;
            a2 += sproj[k] * wv;
        }
        red1[t] = a1; red2[t] = a2;
    }
    __syncthreads();
    if (t < 128) {
        float bb = ldv(gp_b1, t);
        z1g[t] = fmaxf(bb + red1[t] + red1[t + 128], 0.f);
        z1s[t] = fmaxf(bb + red2[t] + red2[t + 128], 0.f);
    }
    __syncthreads();
    {
        int j = t & 63, q = t >> 6;
        int k0 = q * 32;
        float a1 = 0.f, a2 = 0.f;
        #pragma unroll
        for (int kk = 0; kk < 32; ++kk) {
            int k = k0 + kk;
            float wv = ldv(gp_w2, k * 64 + j);
            a1 += z1g[k] * wv;
            a2 += z1s[k] * wv;
        }
        red1[t] = a1; red2[t] = a2;
    }
    __syncthreads();
    if (t < 64) {
        float bb = ldv(gp_b2, t);
        cvec[t]      = fmaxf(bb + red1[t] + red1[t + 64] + red1[t + 128] + red1[t + 192], 0.f);
        cvec[64 + t] = fmaxf(bb + red2[t] + red2[t + 64] + red2[t + 128] + red2[t + 192], 0.f);
    }
    __syncthreads();
    {
        int j = t & 127, khalf = t >> 7;
        int k0 = khalf * 64;
        float a = 0.f;
        #pragma unroll 16
        for (int kk = 0; kk < 64; ++kk) {
            int k = k0 + kk;
            a += cvec[k] * ldv(out_w1, k * 128 + j);
        }
        red1[t] = a;
    }
    __syncthreads();
    if (t < 128) hdn[t] = fmaxf(ldv(out_b1, t) + red1[t] + red1[t + 128], 0.f);
    __syncthreads();
    if (t < 13) {
        float a = ldv(out_b2, t);
        #pragma unroll 16
        for (int k = 0; k < 128; ++k) a += hdn[k] * ldv(out_w2, k * 13 + t);
        outv[t] = a;
    }
}

__global__ __launch_bounds__(256) void k_head(
    const float* __restrict__ gpart, const void* __restrict__ scaf,
    const void* __restrict__ W_sc, const void* __restrict__ b_sc,
    const void* __restrict__ gp_w1, const void* __restrict__ gp_b1,
    const void* __restrict__ gp_w2, const void* __restrict__ gp_b2,
    const void* __restrict__ out_w1, const void* __restrict__ out_b1,
    const void* __restrict__ out_w2, const void* __restrict__ out_b2,
    void* __restrict__ out, const void* __restrict__ Wn) {
    int isbf = sniff(Wn);
    int b = blockIdx.x;
    int t = threadIdx.x;
    __shared__ float gin_s[256], sproj[256], scaf_s[20];
    __shared__ float red1[256], red2[256];
    __shared__ float z1g[128], z1s[128], cvec[128], hdn[128], outv[13];
    if (isbf) {
        head_body<__hip_bfloat16>(b, t, gpart,
            (const __hip_bfloat16*)scaf, (const __hip_bfloat16*)W_sc, (const __hip_bfloat16*)b_sc,
            (const __hip_bfloat16*)gp_w1, (const __hip_bfloat16*)gp_b1,
            (const __hip_bfloat16*)gp_w2, (const __hip_bfloat16*)gp_b2,
            (const __hip_bfloat16*)out_w1, (const __hip_bfloat16*)out_b1,
            (const __hip_bfloat16*)out_w2, (const __hip_bfloat16*)out_b2,
            gin_s, sproj, scaf_s, red1, red2, z1g, z1s, cvec, hdn, outv);
    } else {
        head_body<float>(b, t, gpart,
            (const float*)scaf, (const float*)W_sc, (const float*)b_sc,
            (const float*)gp_w1, (const float*)gp_b1,
            (const float*)gp_w2, (const float*)gp_b2,
            (const float*)out_w1, (const float*)out_b1,
            (const float*)out_w2, (const float*)out_b2,
            gin_s, sproj, scaf_s, red1, red2, z1g, z1s, cvec, hdn, outv);
    }
    __syncthreads();
    if (t < 13) {
        if (isbf) ((__hip_bfloat16*)out)[b * 13 + t] = __float2bfloat16(outv[t]);
        else      ((float*)out)[b * 13 + t] = outv[t];
    }
}

extern "C" void kernel_launch(void* const* d_in, const int* in_sizes, int n_in,
                              void* d_out, int out_size, void* d_ws, size_t ws_size,
                              hipStream_t stream) {
    (void)in_sizes; (void)n_in; (void)out_size; (void)ws_size;
    const void* nf     = d_in[0];
    const int*  adj    = (const int*)d_in[2];
    const void* scaf   = d_in[3];
    const void* W_node = d_in[4];
    const void* b_node = d_in[5];
    const void* gat_W  = d_in[6];
    const void* gat_a  = d_in[7];
    const void* W_sc   = d_in[8];
    const void* b_sc   = d_in[9];
    const void* gp_w1  = d_in[10];
    const void* gp_b1  = d_in[11];
    const void* gp_w2  = d_in[12];
    const void* gp_b2  = d_in[13];
    const void* out_w1 = d_in[14];
    const void* out_b1 = d_in[15];
    const void* out_w2 = d_in[16];
    const void* out_b2 = d_in[17];

    float* ws    = (float*)d_ws;
    float* x     = ws;                 // 1048576 floats
    float* h     = ws + 1048576;       // 1048576 floats
    float* s1    = ws + 2097152;       // 4096
    float* s2    = s1 + 4096;          // 4096
    float* gpart = s2 + 4096;          // 32*16*256 = 131072 floats

    for (int l = 0; l < 3; ++l) {
        k_gat_h<<<256, 256, 0, stream>>>(x, gat_W, gat_a, l,
                                         nf, W_node, b_node, (l == 0) ? 1 : 0,
                                         h, s1, s2);
        k_attn<<<512, 256, 0, stream>>>(h, s1, s2, adj, x, gpart, (l == 2) ? 1 : 0);
    }
    k_head<<<32, 256, 0, stream>>>(gpart, scaf, W_sc, b_sc, gp_w1, gp_b1, gp_w2, gp_b2,
                                   out_w1, out_b1, out_w2, out_b2, d_out, W_node);
}

// Round 7
// 228.195 us; speedup vs baseline: 1.3500x; 1.0374x over previous
//
#include <hip/hip_runtime.h>
#include <hip/hip_bf16.h>

#define NEG_INF -9.0e15f

__device__ __forceinline__ float b2f(__hip_bfloat16 v) { return __bfloat162float(v); }
__device__ __forceinline__ float ldv(const float* p, int i) { return p[i]; }
__device__ __forceinline__ float ldv(const __hip_bfloat16* p, int i) { return __bfloat162float(p[i]); }

__device__ __forceinline__ void unpack8u(uint4 r, float* f) {
    f[0]=__uint_as_float(r.x<<16); f[1]=__uint_as_float(r.x&0xffff0000u);
    f[2]=__uint_as_float(r.y<<16); f[3]=__uint_as_float(r.y&0xffff0000u);
    f[4]=__uint_as_float(r.z<<16); f[5]=__uint_as_float(r.z&0xffff0000u);
    f[6]=__uint_as_float(r.w<<16); f[7]=__uint_as_float(r.w&0xffff0000u);
}
__device__ __forceinline__ void ld8f(const float* p, float* f) {
    const float4* q = (const float4*)p;
    float4 a = q[0], b = q[1];
    f[0]=a.x; f[1]=a.y; f[2]=a.z; f[3]=a.w; f[4]=b.x; f[5]=b.y; f[6]=b.z; f[7]=b.w;
}
__device__ __forceinline__ void ld8f(const __hip_bfloat16* p, float* f) {
    unpack8u(*(const uint4*)p, f);
}

// async global->LDS, 16B per lane (dest = wave-uniform base + lane*16)
__device__ __forceinline__ void async16(const void* g, void* l) {
    __builtin_amdgcn_global_load_lds(
        (__attribute__((address_space(1))) void*)(g),
        (__attribute__((address_space(3))) void*)(l), 16, 0, 0);
}

// wave-level dtype sniff (uniform per wave): bf16 weights -> sane exponents.
__device__ __forceinline__ int sniff(const void* wnode) {
    const unsigned short* w = (const unsigned short*)wnode;
    int lane = threadIdx.x & 63;
    unsigned short u = w[2 * lane];
    int e = (u >> 7) & 0xFF;
    unsigned long long m = __ballot(e >= 100 && e <= 140);
    return __popcll(m) >= 48;
}

// shared epilogue: s1/s2 via half-wave reduction + h stores
template <typename T>
__device__ __forceinline__ void gat_epilogue(
    const T* __restrict__ ga, int tx, int ty, int row0,
    const float* acc0, const float* acc1,
    float* __restrict__ h, float* __restrict__ s1, float* __restrict__ s2) {
    float a1v[8], a2v[8];
    ld8f(ga + 8 * tx, a1v);
    ld8f(ga + 256 + 8 * tx, a2v);
    float d10 = 0.f, d20 = 0.f, d11 = 0.f, d21 = 0.f;
    #pragma unroll
    for (int j = 0; j < 8; ++j) {
        d10 += acc0[j] * a1v[j]; d20 += acc0[j] * a2v[j];
        d11 += acc1[j] * a1v[j]; d21 += acc1[j] * a2v[j];
    }
    #pragma unroll
    for (int off = 1; off < 32; off <<= 1) {   // reduce within each 32-lane half
        d10 += __shfl_xor(d10, off, 64); d20 += __shfl_xor(d20, off, 64);
        d11 += __shfl_xor(d11, off, 64); d21 += __shfl_xor(d21, off, 64);
    }
    if (tx == 0) {                              // lanes 0 and 32 of each wave
        s1[row0 + ty] = d10;     s2[row0 + ty] = d20;
        s1[row0 + ty + 8] = d11; s2[row0 + ty + 8] = d21;
    }
    float4 o00 = {acc0[0], acc0[1], acc0[2], acc0[3]};
    float4 o01 = {acc0[4], acc0[5], acc0[6], acc0[7]};
    float4 o10 = {acc1[0], acc1[1], acc1[2], acc1[3]};
    float4 o11 = {acc1[4], acc1[5], acc1[6], acc1[7]};
    *(float4*)&h[(size_t)(row0 + ty) * 256 + 8 * tx]         = o00;
    *(float4*)&h[(size_t)(row0 + ty) * 256 + 8 * tx + 4]     = o01;
    *(float4*)&h[(size_t)(row0 + ty + 8) * 256 + 8 * tx]     = o10;
    *(float4*)&h[(size_t)(row0 + ty + 8) * 256 + 8 * tx + 4] = o11;
}

// ---------------- gat_h: h = x @ W[l]; s1 = h@a1; s2 = h@a2 -----------------
// 256 blocks x 256 thr. Block = 16 rows x 256 cols. Thread: rows {ty, ty+8},
// cols 8tx..8tx+7. W staged via global_load_lds, 32-k chunks, dbuf,
// per-block chunk-phase stagger to spread L2 same-line concentration.
__global__ __launch_bounds__(256) void k_gat_h(
    const float* __restrict__ x, const void* __restrict__ gat_W,
    const void* __restrict__ gat_a, int layer,
    const void* __restrict__ nf, const void* __restrict__ Wn,
    const void* __restrict__ bn, int first,
    float* __restrict__ h, float* __restrict__ s1, float* __restrict__ s2) {
    __shared__ float xs[16][256];
    __shared__ float nfs[16][80];
    __shared__ __align__(16) unsigned short Wbuf[2][32 * 256];   // 2 x 16 KB
    const int t = threadIdx.x;
    const int row0 = blockIdx.x * 16;
    const int tx = t & 31, ty = t >> 5;
    const int isbf = sniff(Wn);

    if (isbf) {
        const __hip_bfloat16* Wl = (const __hip_bfloat16*)gat_W + (size_t)layer * 65536;
        const __hip_bfloat16* ga = (const __hip_bfloat16*)gat_a + (size_t)layer * 512;
        const int ph = blockIdx.x & 7;      // chunk phase: spread L2 traffic
        // stage chunk region (ph) immediately (overlaps xs preparation)
        {
            const char* g = (const char*)Wl + ph * 16384;
            char* lb = (char*)&Wbuf[0][0];
            #pragma unroll
            for (int i = 0; i < 4; ++i)
                async16(g + i * 4096 + t * 16, lb + i * 4096 + t * 16);
        }
        if (first) {
            for (int idx = t; idx < 16 * 78; idx += 256) {
                int r = idx / 78, k = idx - r * 78;
                nfs[r][k] = b2f(((const __hip_bfloat16*)nf)[(row0 + r) * 78 + k]);
            }
            __syncthreads();
            const __hip_bfloat16* Wnb = (const __hip_bfloat16*)Wn;
            float p0[8], p1[8];
            ld8f((const __hip_bfloat16*)bn + 8 * tx, p0);
            #pragma unroll
            for (int j = 0; j < 8; ++j) p1[j] = p0[j];
            for (int k = 0; k < 78; ++k) {
                float w8[8]; ld8f(Wnb + k * 256 + 8 * tx, w8);
                float xv0 = nfs[ty][k], xv1 = nfs[ty + 8][k];
                #pragma unroll
                for (int j = 0; j < 8; ++j) {
                    p0[j] += xv0 * w8[j];
                    p1[j] += xv1 * w8[j];
                }
            }
            #pragma unroll
            for (int j = 0; j < 8; ++j) {
                xs[ty][8 * tx + j] = p0[j];
                xs[ty + 8][8 * tx + j] = p1[j];
            }
            __syncthreads();
        } else {
            #pragma unroll
            for (int i = 0; i < 4; ++i) {
                int idx = t + 256 * i;             // float4 index into 16x256
                int r = idx >> 6, c4 = idx & 63;
                ((float4*)&xs[r][0])[c4] = ((const float4*)&x[(size_t)(row0 + r) * 256])[c4];
            }
            __syncthreads();
        }
        float acc0[8], acc1[8];
        #pragma unroll
        for (int j = 0; j < 8; ++j) { acc0[j] = 0.f; acc1[j] = 0.f; }
        for (int c = 0; c < 8; ++c) {
            if (c < 7) {
                const char* g = (const char*)Wl + (((c + 1 + ph) & 7) * 16384);
                char* lb = (char*)&Wbuf[(c + 1) & 1][0];
                #pragma unroll
                for (int i = 0; i < 4; ++i)
                    async16(g + i * 4096 + t * 16, lb + i * 4096 + t * 16);
            }
            const unsigned short* Wc = &Wbuf[c & 1][0];
            const int kb = ((c + ph) & 7) * 32;
            #pragma unroll 2
            for (int k0 = 0; k0 < 32; k0 += 4) {
                float4 xa = *(const float4*)&xs[ty][kb + k0];
                float4 xb = *(const float4*)&xs[ty + 8][kb + k0];
                float xav[4] = {xa.x, xa.y, xa.z, xa.w};
                float xbv[4] = {xb.x, xb.y, xb.z, xb.w};
                #pragma unroll
                for (int kk = 0; kk < 4; ++kk) {
                    uint4 wv = *(const uint4*)&Wc[(k0 + kk) * 256 + 8 * tx];
                    float w8[8]; unpack8u(wv, w8);
                    #pragma unroll
                    for (int j = 0; j < 8; ++j) {
                        acc0[j] += xav[kk] * w8[j];
                        acc1[j] += xbv[kk] * w8[j];
                    }
                }
            }
            __syncthreads();   // drains stage(c+1) + releases Wbuf[c&1]
        }
        gat_epilogue<__hip_bfloat16>(ga, tx, ty, row0, acc0, acc1, h, s1, s2);
    } else {
        // f32 fallback: correct, unoptimized
        const float* Wl = (const float*)gat_W + (size_t)layer * 65536;
        const float* ga = (const float*)gat_a + (size_t)layer * 512;
        if (first) {
            for (int idx = t; idx < 16 * 78; idx += 256) {
                int r = idx / 78, k = idx - r * 78;
                nfs[r][k] = ((const float*)nf)[(row0 + r) * 78 + k];
            }
            __syncthreads();
            float p0[8], p1[8];
            ld8f((const float*)bn + 8 * tx, p0);
            #pragma unroll
            for (int j = 0; j < 8; ++j) p1[j] = p0[j];
            for (int k = 0; k < 78; ++k) {
                float w8[8]; ld8f((const float*)Wn + k * 256 + 8 * tx, w8);
                float xv0 = nfs[ty][k], xv1 = nfs[ty + 8][k];
                #pragma unroll
                for (int j = 0; j < 8; ++j) { p0[j] += xv0 * w8[j]; p1[j] += xv1 * w8[j]; }
            }
            #pragma unroll
            for (int j = 0; j < 8; ++j) {
                xs[ty][8 * tx + j] = p0[j];
                xs[ty + 8][8 * tx + j] = p1[j];
            }
            __syncthreads();
        } else {
            #pragma unroll
            for (int i = 0; i < 4; ++i) {
                int idx = t + 256 * i;
                int r = idx >> 6, c4 = idx & 63;
                ((float4*)&xs[r][0])[c4] = ((const float4*)&x[(size_t)(row0 + r) * 256])[c4];
            }
            __syncthreads();
        }
        float acc0[8], acc1[8];
        #pragma unroll
        for (int j = 0; j < 8; ++j) { acc0[j] = 0.f; acc1[j] = 0.f; }
        for (int k = 0; k < 256; ++k) {
            float w8[8]; ld8f(Wl + k * 256 + 8 * tx, w8);
            float xv0 = xs[ty][k], xv1 = xs[ty + 8][k];
            #pragma unroll
            for (int j = 0; j < 8; ++j) { acc0[j] += xv0 * w8[j]; acc1[j] += xv1 * w8[j]; }
        }
        gat_epilogue<float>(ga, tx, ty, row0, acc0, acc1, h, s1, s2);
    }
}

// ---------------- attn: softmax(mask(leaky(s1+s2))) @ h ---------------------
// 512 blocks x 256 thr, block = (b, 8 rows). h staged via global_load_lds in
// 32-row f32 chunks (dbuf) with 4-phase per-block stagger.
__global__ __launch_bounds__(256) void k_attn(
    const float* __restrict__ h, const float* __restrict__ s1,
    const float* __restrict__ s2, const int* __restrict__ adj,
    float* __restrict__ x, float* __restrict__ gpart, int do_pool) {
    __shared__ float att_t[128][10];                 // [col][row], stride 10
    __shared__ __align__(16) float hbuf[2][32 * 256]; // 2 x 32 KB
    __shared__ float pool_red[4][256];
    int blk = blockIdx.x, b = blk >> 4, i0 = (blk & 15) << 3;
    int t = threadIdx.x, w = t >> 6, lane = t & 63;
    const char* hbytes = (const char*)(h + (size_t)b * 32768);
    const int ph = blk & 3;                          // chunk phase
    // stage chunk region (ph) of h — overlaps softmax
    {
        char* lb = (char*)&hbuf[0][0];
        const char* g = hbytes + ph * 32768;
        #pragma unroll
        for (int i = 0; i < 8; ++i)
            async16(g + i * 4096 + t * 16, lb + i * 4096 + t * 16);
    }
    // ---- softmax ----
    {
        int c0 = lane, c1 = lane + 64;
        int ir0 = i0 + 2 * w, ir1 = ir0 + 1;
        const int* a0 = adj + (size_t)(b * 128 + ir0) * 128;
        const int* a1 = adj + (size_t)(b * 128 + ir1) * 128;
        int m00 = a0[c0], m01 = a0[c1], m10 = a1[c0], m11 = a1[c1];
        float sv0 = s1[b * 128 + ir0], sv1 = s1[b * 128 + ir1];
        float t0 = s2[b * 128 + c0],   t1 = s2[b * 128 + c1];
        float e00 = sv0 + t0; e00 = (e00 >= 0.f) ? e00 : 0.2f * e00;
        float e01 = sv0 + t1; e01 = (e01 >= 0.f) ? e01 : 0.2f * e01;
        float e10 = sv1 + t0; e10 = (e10 >= 0.f) ? e10 : 0.2f * e10;
        float e11 = sv1 + t1; e11 = (e11 >= 0.f) ? e11 : 0.2f * e11;
        float v00 = (m00 > 0) ? e00 : NEG_INF;
        float v01 = (m01 > 0) ? e01 : NEG_INF;
        float v10 = (m10 > 0) ? e10 : NEG_INF;
        float v11 = (m11 > 0) ? e11 : NEG_INF;
        float mx0 = fmaxf(v00, v01), mx1 = fmaxf(v10, v11);
        #pragma unroll
        for (int off = 1; off < 64; off <<= 1) {
            mx0 = fmaxf(mx0, __shfl_xor(mx0, off, 64));
            mx1 = fmaxf(mx1, __shfl_xor(mx1, off, 64));
        }
        float p00 = __expf(v00 - mx0), p01 = __expf(v01 - mx0);
        float p10 = __expf(v10 - mx1), p11 = __expf(v11 - mx1);
        float s0 = p00 + p01, ss1 = p10 + p11;
        #pragma unroll
        for (int off = 1; off < 64; off <<= 1) {
            s0  += __shfl_xor(s0, off, 64);
            ss1 += __shfl_xor(ss1, off, 64);
        }
        float inv0 = 1.0f / s0, inv1 = 1.0f / ss1;
        att_t[c0][2 * w]     = p00 * inv0;
        att_t[c1][2 * w]     = p01 * inv0;
        att_t[c0][2 * w + 1] = p10 * inv1;
        att_t[c1][2 * w + 1] = p11 * inv1;
    }
    __syncthreads();   // att_t ready + hbuf[0] staged
    // ---- aggregation: thread = rows {2ty,2ty+1} x cols 4tx, chunked LDS h ----
    int tx = t & 63, ty = t >> 6;
    float acc0[4] = {0.f, 0.f, 0.f, 0.f}, acc1[4] = {0.f, 0.f, 0.f, 0.f};
    for (int c = 0; c < 4; ++c) {
        if (c < 3) {
            char* lb = (char*)&hbuf[(c + 1) & 1][0];
            const char* g = hbytes + (((c + 1 + ph) & 3) * 32768);
            #pragma unroll
            for (int i = 0; i < 8; ++i)
                async16(g + i * 4096 + t * 16, lb + i * 4096 + t * 16);
        }
        const float* hc = &hbuf[c & 1][0];
        const int jb = ((c + ph) & 3) * 32;
        #pragma unroll 4
        for (int jj = 0; jj < 32; ++jj) {
            float4 hv = *(const float4*)&hc[jj * 256 + 4 * tx];
            float2 ap = *(const float2*)&att_t[jb + jj][2 * ty];
            acc0[0] += ap.x * hv.x; acc0[1] += ap.x * hv.y;
            acc0[2] += ap.x * hv.z; acc0[3] += ap.x * hv.w;
            acc1[0] += ap.y * hv.x; acc1[1] += ap.y * hv.y;
            acc1[2] += ap.y * hv.z; acc1[3] += ap.y * hv.w;
        }
        __syncthreads();
    }
    if (!do_pool) {
        float4 o0 = {fmaxf(acc0[0],0.f), fmaxf(acc0[1],0.f), fmaxf(acc0[2],0.f), fmaxf(acc0[3],0.f)};
        float4 o1 = {fmaxf(acc1[0],0.f), fmaxf(acc1[1],0.f), fmaxf(acc1[2],0.f), fmaxf(acc1[3],0.f)};
        *(float4*)&x[(size_t)(b * 128 + i0 + 2 * ty)     * 256 + 4 * tx] = o0;
        *(float4*)&x[(size_t)(b * 128 + i0 + 2 * ty + 1) * 256 + 4 * tx] = o1;
    } else {
        float4 pr = {(fmaxf(acc0[0],0.f) + fmaxf(acc1[0],0.f)) * (1.f/128.f),
                     (fmaxf(acc0[1],0.f) + fmaxf(acc1[1],0.f)) * (1.f/128.f),
                     (fmaxf(acc0[2],0.f) + fmaxf(acc1[2],0.f)) * (1.f/128.f),
                     (fmaxf(acc0[3],0.f) + fmaxf(acc1[3],0.f)) * (1.f/128.f)};
        *(float4*)&pool_red[ty][4 * tx] = pr;
        __syncthreads();
        if (t < 64) {
            float4 r0 = ((const float4*)&pool_red[0][0])[t];
            float4 r1 = ((const float4*)&pool_red[1][0])[t];
            float4 r2 = ((const float4*)&pool_red[2][0])[t];
            float4 r3 = ((const float4*)&pool_red[3][0])[t];
            float4 o = {r0.x+r1.x+r2.x+r3.x, r0.y+r1.y+r2.y+r3.y,
                        r0.z+r1.z+r2.z+r3.z, r0.w+r1.w+r2.w+r3.w};
            *(float4*)&gpart[((size_t)b * 16 + (blk & 15)) * 256 + 4 * t] = o;
        }
    }
}

// ---------------- head: pool MLPs + concat + out MLP ------------------------
template <typename T>
__device__ __forceinline__ void head_body(
    int b, int t, const float* __restrict__ gpart,
    const T* scaf, const T* W_sc, const T* b_sc,
    const T* gp_w1, const T* gp_b1, const T* gp_w2, const T* gp_b2,
    const T* out_w1, const T* out_b1, const T* out_w2, const T* out_b2,
    float* gin_s, float* sproj, float* scaf_s,
    float* red1, float* red2, float* z1g, float* z1s,
    float* cvec, float* hdn, float* outv) {
    float g = 0.f;
    #pragma unroll
    for (int gg = 0; gg < 16; ++gg) g += gpart[((size_t)b * 16 + gg) * 256 + t];
    gin_s[t] = g;
    if (t < 20) scaf_s[t] = ldv(scaf, b * 20 + t);
    __syncthreads();
    {
        float sa = ldv(b_sc, t);
        #pragma unroll
        for (int k = 0; k < 20; ++k) sa += scaf_s[k] * ldv(W_sc, k * 256 + t);
        sproj[t] = sa;
    }
    __syncthreads();
    {
        int j = t & 127, khalf = t >> 7;
        int k0 = khalf * 128;
        float a1 = 0.f, a2 = 0.f;
        #pragma unroll 16
        for (int kk = 0; kk < 128; ++kk) {
            int k = k0 + kk;
            float wv = ldv(gp_w1, k * 128 + j);
            a1 += gin_s[k] * wv;
            a2 += sproj[k] * wv;
        }
        red1[t] = a1; red2[t] = a2;
    }
    __syncthreads();
    if (t < 128) {
        float bb = ldv(gp_b1, t);
        z1g[t] = fmaxf(bb + red1[t] + red1[t + 128], 0.f);
        z1s[t] = fmaxf(bb + red2[t] + red2[t + 128], 0.f);
    }
    __syncthreads();
    {
        int j = t & 63, q = t >> 6;
        int k0 = q * 32;
        float a1 = 0.f, a2 = 0.f;
        #pragma unroll
        for (int kk = 0; kk < 32; ++kk) {
            int k = k0 + kk;
            float wv = ldv(gp_w2, k * 64 + j);
            a1 += z1g[k] * wv;
            a2 += z1s[k] * wv;
        }
        red1[t] = a1; red2[t] = a2;
    }
    __syncthreads();
    if (t < 64) {
        float bb = ldv(gp_b2, t);
        cvec[t]      = fmaxf(bb + red1[t] + red1[t + 64] + red1[t + 128] + red1[t + 192], 0.f);
        cvec[64 + t] = fmaxf(bb + red2[t] + red2[t + 64] + red2[t + 128] + red2[t + 192], 0.f);
    }
    __syncthreads();
    {
        int j = t & 127, khalf = t >> 7;
        int k0 = khalf * 64;
        float a = 0.f;
        #pragma unroll 16
        for (int kk = 0; kk < 64; ++kk) {
            int k = k0 + kk;
            a += cvec[k] * ldv(out_w1, k * 128 + j);
        }
        red1[t] = a;
    }
    __syncthreads();
    if (t < 128) hdn[t] = fmaxf(ldv(out_b1, t) + red1[t] + red1[t + 128], 0.f);
    __syncthreads();
    if (t < 13) {
        float a = ldv(out_b2, t);
        #pragma unroll 16
        for (int k = 0; k < 128; ++k) a += hdn[k] * ldv(out_w2, k * 13 + t);
        outv[t] = a;
    }
}

__global__ __launch_bounds__(256) void k_head(
    const float* __restrict__ gpart, const void* __restrict__ scaf,
    const void* __restrict__ W_sc, const void* __restrict__ b_sc,
    const void* __restrict__ gp_w1, const void* __restrict__ gp_b1,
    const void* __restrict__ gp_w2, const void* __restrict__ gp_b2,
    const void* __restrict__ out_w1, const void* __restrict__ out_b1,
    const void* __restrict__ out_w2, const void* __restrict__ out_b2,
    void* __restrict__ out, const void* __restrict__ Wn) {
    int isbf = sniff(Wn);
    int b = blockIdx.x;
    int t = threadIdx.x;
    __shared__ float gin_s[256], sproj[256], scaf_s[20];
    __shared__ float red1[256], red2[256];
    __shared__ float z1g[128], z1s[128], cvec[128], hdn[128], outv[13];
    if (isbf) {
        head_body<__hip_bfloat16>(b, t, gpart,
            (const __hip_bfloat16*)scaf, (const __hip_bfloat16*)W_sc, (const __hip_bfloat16*)b_sc,
            (const __hip_bfloat16*)gp_w1, (const __hip_bfloat16*)gp_b1,
            (const __hip_bfloat16*)gp_w2, (const __hip_bfloat16*)gp_b2,
            (const __hip_bfloat16*)out_w1, (const __hip_bfloat16*)out_b1,
            (const __hip_bfloat16*)out_w2, (const __hip_bfloat16*)out_b2,
            gin_s, sproj, scaf_s, red1, red2, z1g, z1s, cvec, hdn, outv);
    } else {
        head_body<float>(b, t, gpart,
            (const float*)scaf, (const float*)W_sc, (const float*)b_sc,
            (const float*)gp_w1, (const float*)gp_b1,
            (const float*)gp_w2, (const float*)gp_b2,
            (const float*)out_w1, (const float*)out_b1,
            (const float*)out_w2, (const float*)out_b2,
            gin_s, sproj, scaf_s, red1, red2, z1g, z1s, cvec, hdn, outv);
    }
    __syncthreads();
    if (t < 13) {
        if (isbf) ((__hip_bfloat16*)out)[b * 13 + t] = __float2bfloat16(outv[t]);
        else      ((float*)out)[b * 13 + t] = outv[t];
    }
}

extern "C" void kernel_launch(void* const* d_in, const int* in_sizes, int n_in,
                              void* d_out, int out_size, void* d_ws, size_t ws_size,
                              hipStream_t stream) {
    (void)in_sizes; (void)n_in; (void)out_size; (void)ws_size;
    const void* nf     = d_in[0];
    const int*  adj    = (const int*)d_in[2];
    const void* scaf   = d_in[3];
    const void* W_node = d_in[4];
    const void* b_node = d_in[5];
    const void* gat_W  = d_in[6];
    const void* gat_a  = d_in[7];
    const void* W_sc   = d_in[8];
    const void* b_sc   = d_in[9];
    const void* gp_w1  = d_in[10];
    const void* gp_b1  = d_in[11];
    const void* gp_w2  = d_in[12];
    const void* gp_b2  = d_in[13];
    const void* out_w1 = d_in[14];
    const void* out_b1 = d_in[15];
    const void* out_w2 = d_in[16];
    const void* out_b2 = d_in[17];

    float* ws    = (float*)d_ws;
    float* x     = ws;                 // 1048576 floats
    float* h     = ws + 1048576;       // 1048576 floats
    float* s1    = ws + 2097152;       // 4096
    float* s2    = s1 + 4096;          // 4096
    float* gpart = s2 + 4096;          // 32*16*256 = 131072 floats

    for (int l = 0; l < 3; ++l) {
        k_gat_h<<<256, 256, 0, stream>>>(x, gat_W, gat_a, l,
                                         nf, W_node, b_node, (l == 0) ? 1 : 0,
                                         h, s1, s2);
        k_attn<<<512, 256, 0, stream>>>(h, s1, s2, adj, x, gpart, (l == 2) ? 1 : 0);
    }
    k_head<<<32, 256, 0, stream>>>(gpart, scaf, W_sc, b_sc, gp_w1, gp_b1, gp_w2, gp_b2,
                                   out_w1, out_b1, out_w2, out_b2, d_out, W_node);
}